// Round 6
// baseline (562.754 us; speedup 1.0000x reference)
//
#include <hip/hip_runtime.h>
#include <math.h>

#define PI_D 3.14159265358979323846
#define TWO_PI_F 6.2831853071795864f

// ---------------- persistent device buffers ---------------------------------
__device__ __align__(16) float2  g_Mf [128*128];
__device__ __align__(16) float2  g_Mb [128*128];
__device__ __align__(16) float2  g_F  [128*128];
__device__ __align__(16) float2  g_IF [128*128];
__device__ __align__(16) float   g_x1 [4*48*16384];
__device__ __align__(16) float2  g_bufA[64*16384];
__device__ __align__(16) float   g_mag[64*16384];
__device__ __align__(16) float   g_pha[64*16384];
__device__ __align__(16) float   g_t1 [64*16384];
__device__ __align__(16) float   g_t2 [64*16384];
__device__ __align__(16) float   g_cat[4*48*16384];

// ---------------- matrix builders -------------------------------------------
__global__ void k_build_M05f() {
    int tid = blockIdx.x*blockDim.x + threadIdx.x;
    if (tid >= 128*128) return;
    int o = tid >> 7, m = tid & 127;
    const double chc = -PI_D/128.0 * tan(PI_D/8.0) * 0.25;
    const double c   =  PI_D/(512.0*sin(PI_D/4.0));
    const double inv2pi = 1.0/(2.0*PI_D);
    float sr, si;
    {   // q = 2m term (sinc = 1)
        int n1 = 2*m - 127, tt = 2*(o - m);
        double ang = chc*(double)(n1*n1) + c*(double)(tt*tt);
        double r = ang*inv2pi; r -= floor(r);
        float af = (float)(r*2.0*PI_D);
        float sn, cs; __sincosf(af, &sn, &cs);
        sr = cs; si = sn;
    }
    for (int j = 0; j < 127; ++j) {
        int q  = 2*j + 1;
        int n1 = q - 127, tt = 2*o - q, d = q - 2*m;
        double ang = chc*(double)(n1*n1) + c*(double)(tt*tt);
        double r = ang*inv2pi; r -= floor(r);
        float af = (float)(r*2.0*PI_D);
        float s = (((d-1)>>1) & 1) ? -2.0f : 2.0f;
        s /= (3.14159265358979f*(float)d);
        float sn, cs; __sincosf(af, &sn, &cs);
        sr += s*cs; si += s*sn;
    }
    int n2 = 2*o - 127;
    double ph = chc*(double)(n2*n2) - PI_D/8.0;
    double r = ph*inv2pi; r -= floor(r);
    float pf = (float)(r*2.0*PI_D);
    float scale = (float)sqrt(c/PI_D);
    float sn, cs; __sincosf(pf, &sn, &cs);
    float cr = cs*scale, ci = sn*scale;
    g_Mf[tid] = make_float2(sr*cr - si*ci, sr*ci + si*cr);
}

__global__ void k_build_Mbf() {
    __shared__ float2 W[128];
    int t = threadIdx.x;
    for (int i = t; i < 128; i += 64) {
        float ang = TWO_PI_F*(float)i/128.0f;
        float sn, cs; sincosf(ang, &sn, &cs);
        float invs = 0.08838834764831845f;
        W[i] = make_float2(cs*invs, sn*invs);
    }
    __syncthreads();
    int tid = blockIdx.x*blockDim.x + t;
    if (tid >= 128*128) return;
    int o = tid >> 7, m = tid & 127;
    float sr = 0.f, si = 0.f;
    for (int r = 0; r < 128; ++r) {
        float2 a = g_Mf[(o<<7) + r];
        int k = ((r+64)*(m+64)) & 127;
        float2 w = W[k];
        sr += a.x*w.x - a.y*w.y;
        si += a.x*w.y + a.y*w.x;
    }
    g_Mb[tid] = make_float2(sr, si);
}

__global__ void k_build_Ff() {
    int tid = blockIdx.x*blockDim.x + threadIdx.x;
    if (tid >= 128*128) return;
    int k = tid >> 7, n = tid & 127;
    int p = (k*n) & 127;
    float ang = TWO_PI_F*(float)p/128.0f;
    float sn, cs; sincosf(ang, &sn, &cs);
    g_F[tid]  = make_float2(cs, -sn);
    g_IF[tid] = make_float2(cs*0.0078125f, sn*0.0078125f);
}

// ---------------- transform GEMMs: 32x64 tiles, 256 thr, 4x2 micro ----------
// Loader modes: 0 complex natural  1 real from x1 slice
// 2 mag/pha full (fused combine)   3 mag/pha packed65 + Hermitian
template<int LM>
__device__ inline void load_T4(float2* tr, const float* mp, const float* pp,
                               const float2* Tc, const float* Trl,
                               int hh, int w4) {
    if (LM == 0) {
        const float4* src = (const float4*)(Tc + (hh<<7) + w4);
        float4 a = src[0], b = src[1];
        tr[0] = make_float2(a.x, a.y); tr[1] = make_float2(a.z, a.w);
        tr[2] = make_float2(b.x, b.y); tr[3] = make_float2(b.z, b.w);
    } else if (LM == 1) {
        float4 v = *(const float4*)(Trl + (hh<<7) + w4);
        tr[0] = make_float2(v.x, 0.f); tr[1] = make_float2(v.y, 0.f);
        tr[2] = make_float2(v.z, 0.f); tr[3] = make_float2(v.w, 0.f);
    } else if (LM == 2) {
#pragma unroll
        for (int i = 0; i < 4; ++i) {
            int idx = (hh<<7) + w4 + i;
            float m = mp[idx], ph = pp[idx];
            float sn, cs; __sincosf(ph, &sn, &cs);
            tr[i] = make_float2(m*cs, m*sn);
        }
    } else {
#pragma unroll
        for (int i = 0; i < 4; ++i) {
            int w = w4 + i;
            int h2 = hh, w2 = w; float sg = 1.f;
            if (w >= 65) { h2 = (128 - hh) & 127; w2 = 128 - w; sg = -1.f; }
            int idx = h2*65 + w2;
            float m = mp[idx], ph = pp[idx];
            float sn, cs; __sincosf(ph, &sn, &cs);
            tr[i] = make_float2(m*cs, sg*m*sn);
        }
    }
}

// out[p,h,j] = sum_w T[p,h,w] * A[j,w]   — 32h x 64j tile
template<int LM>
__global__ __launch_bounds__(256, 2)
void k_rmul32(const float2* __restrict__ A, const float2* __restrict__ Tc,
              const float* __restrict__ Trl, const float* __restrict__ mp_,
              const float* __restrict__ pp_, float2* __restrict__ out,
              int Ctot, int Csub, int cstart) {
    __shared__ float2 Ts[32][33];   // [h][k]
    __shared__ float2 As[64][33];   // [j][k]
    int p  = blockIdx.z;
    int h0 = blockIdx.y << 5, j0 = blockIdx.x << 6;
    int t  = threadIdx.x;
    int tx = t & 31, ty = t >> 5;          // h = h0+4ty+i, j = j0+tx(+32)
    int tlr = t >> 3, tl4 = (t & 7) * 4;   // Ts staging: 32 rows x 4
    int alr = t >> 2, ak8 = (t & 3) * 8;   // As staging: 64 rows x 8
    const float2* Tcp = nullptr; const float* Trp = nullptr;
    const float* mp = nullptr; const float* pp = nullptr;
    if (LM == 0) Tcp = Tc + ((long)p << 14);
    if (LM == 1) { int n = p / Csub, c = p - n*Csub; Trp = Trl + ((long)(n*Ctot + cstart + c) << 14); }
    if (LM == 2) { mp = mp_ + ((long)p << 14); pp = pp_ + ((long)p << 14); }
    if (LM == 3) { mp = mp_ + (long)p*8320;   pp = pp_ + (long)p*8320; }
    float2 acc[4][2] = {};
    for (int kc = 0; kc < 128; kc += 32) {
        __syncthreads();
        {
            float2 tr4[4];
            load_T4<LM>(tr4, mp, pp, Tcp, Trp, h0 + tlr, kc + tl4);
#pragma unroll
            for (int i = 0; i < 4; ++i) Ts[tlr][tl4 + i] = tr4[i];
            const float4* sA = (const float4*)(A + ((j0 + alr) << 7) + kc + ak8);
            float4 a0 = sA[0], a1 = sA[1];
            As[alr][ak8 + 0] = make_float2(a0.x, a0.y);
            As[alr][ak8 + 1] = make_float2(a0.z, a0.w);
            As[alr][ak8 + 2] = make_float2(a1.x, a1.y);
            As[alr][ak8 + 3] = make_float2(a1.z, a1.w);
            const float4* sA2 = sA + 2;
            float4 a2 = sA2[0], a3 = sA2[1];
            As[alr][ak8 + 4] = make_float2(a2.x, a2.y);
            As[alr][ak8 + 5] = make_float2(a2.z, a2.w);
            As[alr][ak8 + 6] = make_float2(a3.x, a3.y);
            As[alr][ak8 + 7] = make_float2(a3.z, a3.w);
        }
        __syncthreads();
#pragma unroll
        for (int kk = 0; kk < 32; ++kk) {
            float2 av[4], bv[2];
#pragma unroll
            for (int i = 0; i < 4; ++i) av[i] = Ts[4*ty + i][kk];
            bv[0] = As[tx][kk]; bv[1] = As[tx + 32][kk];
#pragma unroll
            for (int i = 0; i < 4; ++i)
#pragma unroll
                for (int j = 0; j < 2; ++j) {
                    acc[i][j].x += av[i].x*bv[j].x - av[i].y*bv[j].y;
                    acc[i][j].y += av[i].x*bv[j].y + av[i].y*bv[j].x;
                }
        }
    }
    long base = ((long)p << 14);
#pragma unroll
    for (int i = 0; i < 4; ++i) {
        out[base + ((h0 + 4*ty + i) << 7) + j0 + tx]      = acc[i][0];
        out[base + ((h0 + 4*ty + i) << 7) + j0 + tx + 32] = acc[i][1];
    }
}

// out[p,j,w] = sum_h A[j,h] * T[p,h,w]   — 32j x 64w tile; fused epilogues:
// EPI 1: mag/pha full -> o1,o2   2: abs->cat+coff   3: real-only->cat+coff
// EPI 4: mag/pha packed w<65 -> o1,o2
template<int EPI>
__global__ __launch_bounds__(256, 2)
void k_lmul32(const float2* __restrict__ A, const float2* __restrict__ in,
              float* __restrict__ o1, float* __restrict__ o2, int coff) {
    __shared__ float2 As[32][33];   // [j][k]
    __shared__ float2 Ts[32][66];   // [k][w]
    int p  = blockIdx.z;
    int j0 = blockIdx.y << 5, w0 = blockIdx.x << 6;
    int t  = threadIdx.x;
    int tx = t & 31, ty = t >> 5;
    int alr = t >> 3, al4 = (t & 7) * 4;   // As staging: 32 rows x 4
    int tkr = t >> 3, tw8 = (t & 7) * 8;   // Ts staging: 32 k-rows x 8 w
    const float2* T = in + ((long)p << 14);
    float2 acc[4][2] = {};
    for (int kc = 0; kc < 128; kc += 32) {
        __syncthreads();
        {
            const float4* sA = (const float4*)(A + ((j0 + alr) << 7) + kc + al4);
            float4 a0 = sA[0], a1 = sA[1];
            As[alr][al4 + 0] = make_float2(a0.x, a0.y);
            As[alr][al4 + 1] = make_float2(a0.z, a0.w);
            As[alr][al4 + 2] = make_float2(a1.x, a1.y);
            As[alr][al4 + 3] = make_float2(a1.z, a1.w);
            const float4* sT = (const float4*)(T + ((kc + tkr) << 7) + w0 + tw8);
            float4* dT = (float4*)&Ts[tkr][tw8];
            dT[0] = sT[0]; dT[1] = sT[1];
            dT[2] = sT[2]; dT[3] = sT[3];
        }
        __syncthreads();
#pragma unroll
        for (int kk = 0; kk < 32; ++kk) {
            float2 av[4], bv[2];
#pragma unroll
            for (int i = 0; i < 4; ++i) av[i] = As[4*ty + i][kk];
            bv[0] = Ts[kk][tx]; bv[1] = Ts[kk][tx + 32];
#pragma unroll
            for (int i = 0; i < 4; ++i)
#pragma unroll
                for (int j = 0; j < 2; ++j) {
                    if (EPI == 3) {
                        acc[i][j].x += av[i].x*bv[j].x - av[i].y*bv[j].y;
                    } else {
                        acc[i][j].x += av[i].x*bv[j].x - av[i].y*bv[j].y;
                        acc[i][j].y += av[i].x*bv[j].y + av[i].y*bv[j].x;
                    }
                }
        }
    }
#pragma unroll
    for (int i = 0; i < 4; ++i) {
#pragma unroll
        for (int j = 0; j < 2; ++j) {
            int jj = j0 + 4*ty + i;
            int ww = w0 + tx + 32*j;
            float2 v = acc[i][j];
            if (EPI == 1) {
                long idx = ((long)p << 14) + (jj << 7) + ww;
                o1[idx] = sqrtf(v.x*v.x + v.y*v.y);
                o2[idx] = atan2f(v.y, v.x);
            } else if (EPI == 2) {
                int n = p >> 4, c = p & 15;
                o1[((long)(n*48 + coff + c) << 14) + (jj << 7) + ww] = sqrtf(v.x*v.x + v.y*v.y);
            } else if (EPI == 3) {
                int n = p >> 4, c = p & 15;
                o1[((long)(n*48 + coff + c) << 14) + (jj << 7) + ww] = v.x;
            } else if (EPI == 4) {
                if (ww < 65) {
                    long idx = (long)p*8320 + jj*65 + ww;
                    o1[idx] = sqrtf(v.x*v.x + v.y*v.y);
                    o2[idx] = atan2f(v.y, v.x);
                }
            }
        }
    }
}

// ---------------- wave-level 1x1 conv ---------------------------------------
// Block = 4 waves; lane = spatial position; wave (oq,kq) covers OW outputs x
// KC input channels. KSPLIT>1 -> one LDS reduction at the end (no loop barriers).
template<int CIN, int COUT, int KSPLIT, int OSPLIT>
__global__ __launch_bounds__(256, 2)
void k_wconv(const float* __restrict__ in, const float* __restrict__ wgt,
             const float* __restrict__ bias, float* __restrict__ out,
             int S, int Ctin, int cstart, int Ctout, int costart) {
    constexpr int OW = COUT / OSPLIT;
    constexpr int KC = CIN / KSPLIT;
    constexpr int RSZ = (KSPLIT > 1) ? KSPLIT * COUT * 64 : 1;
    __shared__ float red[RSZ];
    int t = threadIdx.x, lane = t & 63;
    int wv = __builtin_amdgcn_readfirstlane(t >> 6);
    int oq = wv / KSPLIT, kq = wv % KSPLIT;
    int n = blockIdx.y;
    int s0 = blockIdx.x * 64;
    const float* inb = in + ((long)(n*Ctin + cstart + kq*KC))*S + s0 + lane;
    const float* wb  = wgt + (oq*OW)*CIN + kq*KC;
    float acc[OW] = {};
#pragma unroll 4
    for (int c = 0; c < KC; ++c) {
        float xv = inb[(long)c*S];
#pragma unroll
        for (int j = 0; j < OW; ++j)
            acc[j] = fmaf(wb[j*CIN + c], xv, acc[j]);
    }
    if (KSPLIT == 1) {
#pragma unroll
        for (int j = 0; j < OW; ++j) {
            int o = oq*OW + j;
            float v = acc[j] + (bias ? bias[o] : 0.f);
            out[((long)(n*Ctout + costart + o))*S + s0 + lane] = v;
        }
    } else {
#pragma unroll
        for (int j = 0; j < OW; ++j)
            red[(kq*COUT + oq*OW + j)*64 + lane] = acc[j];
        __syncthreads();
        for (int idx = t; idx < COUT*64; idx += 256) {
            int o = idx >> 6, l = idx & 63;
            float v = bias ? bias[o] : 0.f;
#pragma unroll
            for (int k2 = 0; k2 < KSPLIT; ++k2)
                v += red[(k2*COUT + o)*64 + l];
            out[((long)(n*Ctout + costart + o))*S + s0 + l] = v;
        }
    }
}

// ---------------- maskconv: LDS-tiled, branchless 3x3 -----------------------
__global__ __launch_bounds__(256, 2)
void k_maskconv2(const float* __restrict__ mag, const float* __restrict__ ws3,
                 const float* __restrict__ bs, const float* __restrict__ wf,
                 const float* __restrict__ bf, float* __restrict__ out) {
    __shared__ float patch[16][324];   // 18x18 per channel, mask1 applied
    int n = blockIdx.y;
    int h0 = (blockIdx.x >> 3) << 4, w0 = (blockIdx.x & 7) << 4;
    int t = threadIdx.x;
    const float* magn = mag + ((long)n << 18);
    for (int idx = t; idx < 16*324; idx += 256) {
        int c = idx / 324, r = idx - c*324;
        int ph = r / 18, pw = r - ph*18;
        int gh = h0 - 1 + ph, gw = w0 - 1 + pw;
        float v = 0.f;
        if (gh >= 19 && gh < 109 && gw >= 19 && gw < 109)
            v = magn[(c<<14) + (gh<<7) + gw];
        patch[c][r] = v;
    }
    __syncthreads();
    int ty = t >> 4, tx = t & 15;
    int h = h0 + ty, w = w0 + tx;
    bool in1 = (h >= 19 && h < 109 && w >= 19 && w < 109);
    unsigned long long bal = __ballot(in1);
    float res[16];
    if (bal != 0ull) {
        float acc[16];
#pragma unroll
        for (int o = 0; o < 16; ++o) acc[o] = bs[o];
        for (int c = 0; c < 16; ++c) {
            float tap[9];
#pragma unroll
            for (int dh = 0; dh < 3; ++dh)
#pragma unroll
                for (int dw = 0; dw < 3; ++dw)
                    tap[dh*3+dw] = patch[c][(ty+dh)*18 + tx+dw];
            const float* wp = ws3 + c*9;
#pragma unroll
            for (int o = 0; o < 16; ++o)
#pragma unroll
                for (int k = 0; k < 9; ++k)
                    acc[o] = fmaf(wp[o*144 + k], tap[k], acc[o]);
        }
#pragma unroll
        for (int o = 0; o < 16; ++o) res[o] = acc[o];
    }
    if (bal != ~0ull) {
        float xv[16];
#pragma unroll
        for (int c = 0; c < 16; ++c) xv[c] = magn[(c<<14) + (h<<7) + w];
#pragma unroll
        for (int o = 0; o < 16; ++o) {
            float a = bf[o];
#pragma unroll
            for (int c = 0; c < 16; ++c) a = fmaf(wf[o*16 + c], xv[c], a);
            if (!in1) res[o] = a;
        }
    }
#pragma unroll
    for (int o = 0; o < 16; ++o)
        out[((long)((n<<4) + o) << 14) + (h << 7) + w] = res[o];
}

// ---------------- launch ----------------------------------------------------
extern "C" void kernel_launch(void* const* d_in, const int* in_sizes, int n_in,
                              void* d_out, int out_size, void* d_ws, size_t ws_size,
                              hipStream_t stream) {
    (void)in_sizes; (void)n_in; (void)out_size; (void)d_ws; (void)ws_size;
    const float* x        = (const float*)d_in[0];
    const float* conv1_w  = (const float*)d_in[1];
    const float* mag_s_w  = (const float*)d_in[2];
    const float* mag_s_b  = (const float*)d_in[3];
    const float* mag_f_w  = (const float*)d_in[4];
    const float* mag_f_b  = (const float*)d_in[5];
    const float* mag_w_   = (const float*)d_in[6];
    const float* mag_b_   = (const float*)d_in[7];
    const float* pha_w_   = (const float*)d_in[8];
    const float* pha_b_   = (const float*)d_in[9];
    const float* conv_0_w = (const float*)d_in[10];
    const float* conv_0_b = (const float*)d_in[11];
    const float* conv_1_w = (const float*)d_in[12];
    const float* conv_1_b = (const float*)d_in[13];
    const float* conv2_w  = (const float*)d_in[14];
    float* outp = (float*)d_out;

    float2 *Mf, *Mb, *Fm, *IFm, *bufA;
    float *x1, *mag, *pha, *t1, *t2, *cat;
    hipGetSymbolAddress((void**)&Mf,   HIP_SYMBOL(g_Mf));
    hipGetSymbolAddress((void**)&Mb,   HIP_SYMBOL(g_Mb));
    hipGetSymbolAddress((void**)&Fm,   HIP_SYMBOL(g_F));
    hipGetSymbolAddress((void**)&IFm,  HIP_SYMBOL(g_IF));
    hipGetSymbolAddress((void**)&bufA, HIP_SYMBOL(g_bufA));
    hipGetSymbolAddress((void**)&x1,   HIP_SYMBOL(g_x1));
    hipGetSymbolAddress((void**)&mag,  HIP_SYMBOL(g_mag));
    hipGetSymbolAddress((void**)&pha,  HIP_SYMBOL(g_pha));
    hipGetSymbolAddress((void**)&t1,   HIP_SYMBOL(g_t1));
    hipGetSymbolAddress((void**)&t2,   HIP_SYMBOL(g_t2));
    hipGetSymbolAddress((void**)&cat,  HIP_SYMBOL(g_cat));

    dim3 gr(2,4,64), gl(2,4,64), bt(256,1,1);

    // matrices
    k_build_M05f<<<256, 64, 0, stream>>>();
    k_build_Mbf <<<256, 64, 0, stream>>>();
    k_build_Ff  <<<256, 64, 0, stream>>>();

    // x1 = 1x1 conv (192 -> 48), K split across 4 waves
    k_wconv<192,48,4,1><<<dim3(256,4), 256, 0, stream>>>(x, conv1_w, nullptr, x1, 16384, 192, 0, 48, 0);

    // FRFT forward on x_05 (ch 16..31): Fre = Mf X Mf^T; fused mag/pha
    k_rmul32<1><<<gr, bt, 0, stream>>>(Mf, nullptr, x1, nullptr, nullptr, bufA, 48, 16, 16);
    k_lmul32<1><<<gl, bt, 0, stream>>>(Mf, bufA, mag, pha, 0);

    // masked convs + channel mixes
    k_maskconv2<<<dim3(64,4), 256, 0, stream>>>(mag, mag_s_w, mag_s_b, mag_f_w, mag_f_b, t1);
    k_wconv<16,16,2,2><<<dim3(256,4), 256, 0, stream>>>(t1,  mag_w_, mag_b_, t2, 16384, 16, 0, 16, 0);
    k_wconv<16,16,2,2><<<dim3(256,4), 256, 0, stream>>>(pha, pha_w_, pha_b_, t1, 16384, 16, 0, 16, 0);

    // FRFT backward (combine fused into loader): |Mb Y Mb^T| -> cat ch 16..31
    k_rmul32<2><<<gr, bt, 0, stream>>>(Mb, nullptr, nullptr, t2, t1, bufA, 0, 0, 0);
    k_lmul32<2><<<gl, bt, 0, stream>>>(Mb, bufA, cat, nullptr, 16);

    // FFT branch on x_1 (ch 32..47): G = F X F^T; fused packed mag/pha
    k_rmul32<1><<<gr, bt, 0, stream>>>(Fm, nullptr, x1, nullptr, nullptr, bufA, 48, 16, 32);
    k_lmul32<4><<<gl, bt, 0, stream>>>(Fm, bufA, mag, pha, 0);
    k_wconv<16,16,2,2><<<dim3(130,4), 256, 0, stream>>>(mag, conv_1_w, conv_1_b, t1, 8320, 16, 0, 16, 0);
    k_wconv<16,16,2,2><<<dim3(130,4), 256, 0, stream>>>(pha, conv_1_w, conv_1_b, t2, 8320, 16, 0, 16, 0);
    // inverse rfft2 (combine65 + Hermitian extension fused into loader)
    k_rmul32<3><<<gr, bt, 0, stream>>>(IFm, nullptr, nullptr, t1, t2, bufA, 0, 0, 0);
    k_lmul32<3><<<gl, bt, 0, stream>>>(IFm, bufA, cat, nullptr, 32);

    // x_0o -> cat ch 0..15
    k_wconv<16,16,2,2><<<dim3(256,4), 256, 0, stream>>>(x1, conv_0_w, conv_0_b, cat, 16384, 48, 0, 48, 0);

    // final 1x1 conv (48 -> 192), outputs split across 4 waves
    k_wconv<48,192,1,4><<<dim3(256,4), 256, 0, stream>>>(cat, conv2_w, nullptr, outp, 16384, 48, 0, 192, 0);
}

// Round 7
// 433.548 us; speedup vs baseline: 1.2980x; 1.2980x over previous
//
#include <hip/hip_runtime.h>
#include <math.h>

#define PI_D 3.14159265358979323846
#define TWO_PI_F 6.2831853071795864f

// ---------------- persistent device buffers ---------------------------------
__device__ __align__(16) float2 g_Mf [128*128];
__device__ __align__(16) float2 g_MfT[128*128];
__device__ __align__(16) float2 g_Mb [128*128];
__device__ __align__(16) float2 g_MbT[128*128];
__device__ __align__(16) float2 g_F  [128*128];   // symmetric: natural == transposed
__device__ __align__(16) float2 g_IF [128*128];   // symmetric
__device__ __align__(16) float  g_x1 [4*48*16384];
__device__ __align__(16) float2 g_bufA[64*16384];
__device__ __align__(16) float  g_mag[64*16384];
__device__ __align__(16) float  g_pha[64*16384];
__device__ __align__(16) float  g_t1 [64*16384];
__device__ __align__(16) float  g_t2 [64*16384];
__device__ __align__(16) float  g_cat[4*48*16384];

// ---------------- matrix builders -------------------------------------------
__global__ void k_build_M05f() {
    int tid = blockIdx.x*blockDim.x + threadIdx.x;
    if (tid >= 128*128) return;
    int o = tid >> 7, m = tid & 127;
    const double chc = -PI_D/128.0 * tan(PI_D/8.0) * 0.25;
    const double c   =  PI_D/(512.0*sin(PI_D/4.0));
    const double inv2pi = 1.0/(2.0*PI_D);
    float sr, si;
    {   // q = 2m term (sinc = 1)
        int n1 = 2*m - 127, tt = 2*(o - m);
        double ang = chc*(double)(n1*n1) + c*(double)(tt*tt);
        double r = ang*inv2pi; r -= floor(r);
        float af = (float)(r*2.0*PI_D);
        float sn, cs; __sincosf(af, &sn, &cs);
        sr = cs; si = sn;
    }
    for (int j = 0; j < 127; ++j) {
        int q  = 2*j + 1;
        int n1 = q - 127, tt = 2*o - q, d = q - 2*m;
        double ang = chc*(double)(n1*n1) + c*(double)(tt*tt);
        double r = ang*inv2pi; r -= floor(r);
        float af = (float)(r*2.0*PI_D);
        float s = (((d-1)>>1) & 1) ? -2.0f : 2.0f;
        s /= (3.14159265358979f*(float)d);
        float sn, cs; __sincosf(af, &sn, &cs);
        sr += s*cs; si += s*sn;
    }
    int n2 = 2*o - 127;
    double ph = chc*(double)(n2*n2) - PI_D/8.0;
    double r = ph*inv2pi; r -= floor(r);
    float pf = (float)(r*2.0*PI_D);
    float scale = (float)sqrt(c/PI_D);
    float sn, cs; __sincosf(pf, &sn, &cs);
    float cr = cs*scale, ci = sn*scale;
    float2 v = make_float2(sr*cr - si*ci, sr*ci + si*cr);
    g_Mf[tid] = v;
    g_MfT[(m<<7) + o] = v;
}

__global__ void k_build_Mbf() {
    __shared__ float2 W[128];
    int t = threadIdx.x;
    for (int i = t; i < 128; i += 64) {
        float ang = TWO_PI_F*(float)i/128.0f;
        float sn, cs; sincosf(ang, &sn, &cs);
        float invs = 0.08838834764831845f;
        W[i] = make_float2(cs*invs, sn*invs);
    }
    __syncthreads();
    int tid = blockIdx.x*blockDim.x + t;
    if (tid >= 128*128) return;
    int o = tid >> 7, m = tid & 127;
    float sr = 0.f, si = 0.f;
    for (int r = 0; r < 128; ++r) {
        float2 a = g_Mf[(o<<7) + r];
        int k = ((r+64)*(m+64)) & 127;
        float2 w = W[k];
        sr += a.x*w.x - a.y*w.y;
        si += a.x*w.y + a.y*w.x;
    }
    float2 v = make_float2(sr, si);
    g_Mb[tid] = v;
    g_MbT[(m<<7) + o] = v;
}

__global__ void k_build_Ff() {
    int tid = blockIdx.x*blockDim.x + threadIdx.x;
    if (tid >= 128*128) return;
    int k = tid >> 7, n = tid & 127;
    int p = (k*n) & 127;
    float ang = TWO_PI_F*(float)p/128.0f;
    float sn, cs; sincosf(ang, &sn, &cs);
    g_F[tid]  = make_float2(cs, -sn);
    g_IF[tid] = make_float2(cs*0.0078125f, sn*0.0078125f);
}

// ---------------- stream loaders (rmul T-side) -------------------------------
// LM 1: real from x1 slice   2: mag/pha full plane   3: mag/pha packed65 + Hermitian
template<int LM>
__device__ inline void load_T4(float2* tr, const float* mp, const float* pp,
                               const float* Trl, int hh, int w4) {
    if (LM == 1) {
        float4 v = *(const float4*)(Trl + (hh<<7) + w4);
        tr[0] = make_float2(v.x, 0.f); tr[1] = make_float2(v.y, 0.f);
        tr[2] = make_float2(v.z, 0.f); tr[3] = make_float2(v.w, 0.f);
    } else if (LM == 2) {
#pragma unroll
        for (int i = 0; i < 4; ++i) {
            int idx = (hh<<7) + w4 + i;
            float m = mp[idx], ph = pp[idx];
            float sn, cs; __sincosf(ph, &sn, &cs);
            tr[i] = make_float2(m*cs, m*sn);
        }
    } else {
#pragma unroll
        for (int i = 0; i < 4; ++i) {
            int w = w4 + i;
            int h2 = hh, w2 = w; float sg = 1.f;
            if (w >= 65) { h2 = (128 - hh) & 127; w2 = 128 - w; sg = -1.f; }
            int idx = h2*65 + w2;
            float m = mp[idx], ph = pp[idx];
            float sn, cs; __sincosf(ph, &sn, &cs);
            tr[i] = make_float2(m*cs, sg*m*sn);
        }
    }
}

// ---------------- rmul: out[p,h,j] = sum_w T[p,h,w] * A[j,w] -----------------
// MT = A transposed [w][j]; 32-row strip resident in LDS, MT chunked.
template<int LM>
__global__ __launch_bounds__(256, 1)
void k_rmulT(const float2* __restrict__ MT, const float* __restrict__ Trl,
             const float* __restrict__ mp_, const float* __restrict__ pp_,
             float2* __restrict__ out, int Ctot, int Csub, int cstart) {
    constexpr bool RS = (LM == 1);
    __shared__ float2 Ssh[32*128];   // [r][k]  stream strip
    __shared__ float2 Mch[32*128];   // [k][j]  resident chunk
    int p  = blockIdx.y;
    int r0 = blockIdx.x << 5;
    int t  = threadIdx.x;
    const float* Trp = nullptr; const float* mp = nullptr; const float* pp = nullptr;
    if (LM == 1) { int n = p / Csub, c = p - n*Csub; Trp = Trl + ((long)(n*Ctot + cstart + c) << 14); }
    if (LM == 2) { mp = mp_ + ((long)p << 14); pp = pp_ + ((long)p << 14); }
    if (LM == 3) { mp = mp_ + (long)p*8320;   pp = pp_ + (long)p*8320; }
    // stage stream strip (32 rows x 128 k)
    for (int u = t; u < 1024; u += 256) {
        int row = u >> 5, w4 = (u & 31) << 2;
        float2 tr4[4];
        load_T4<LM>(tr4, mp, pp, Trp, r0 + row, w4);
        float4* d = (float4*)&Ssh[(row << 7) + w4];
        d[0] = make_float4(tr4[0].x, tr4[0].y, tr4[1].x, tr4[1].y);
        d[1] = make_float4(tr4[2].x, tr4[2].y, tr4[3].x, tr4[3].y);
    }
    float2 acc[4][4] = {};
    int jq = t & 31, rp = t >> 5;
    for (int kc = 0; kc < 128; kc += 32) {
        __syncthreads();
        {
            const float4* Mg = (const float4*)(MT + (kc << 7));
            float4* Md = (float4*)Mch;
            for (int i = t; i < 2048; i += 256) Md[i] = Mg[i];
        }
        __syncthreads();
#pragma unroll
        for (int kk = 0; kk < 32; ++kk) {
            int k = kc + kk;
            float2 s[4], m[4];
#pragma unroll
            for (int i = 0; i < 4; ++i) s[i] = Ssh[(((rp<<2)+i) << 7) + k];
#pragma unroll
            for (int q = 0; q < 4; ++q) m[q] = Mch[(kk << 7) + jq + (q<<5)];
#pragma unroll
            for (int i = 0; i < 4; ++i)
#pragma unroll
                for (int q = 0; q < 4; ++q) {
                    if (RS) {
                        acc[i][q].x = fmaf(s[i].x, m[q].x, acc[i][q].x);
                        acc[i][q].y = fmaf(s[i].x, m[q].y, acc[i][q].y);
                    } else {
                        acc[i][q].x = fmaf(s[i].x, m[q].x, acc[i][q].x);
                        acc[i][q].x = fmaf(-s[i].y, m[q].y, acc[i][q].x);
                        acc[i][q].y = fmaf(s[i].x, m[q].y, acc[i][q].y);
                        acc[i][q].y = fmaf(s[i].y, m[q].x, acc[i][q].y);
                    }
                }
        }
    }
    long base = ((long)p << 14);
#pragma unroll
    for (int i = 0; i < 4; ++i)
#pragma unroll
        for (int q = 0; q < 4; ++q)
            out[base + ((long)(r0 + (rp<<2) + i) << 7) + jq + (q<<5)] = acc[i][q];
}

// ---------------- lmul: out[p,j,w] = sum_h A[j,h] * T[p,h,w] -----------------
// Stream = A rows (natural); resident = T plane chunked. Fused epilogues:
// EPI 1: mag/pha full -> o1,o2   2: abs->cat+coff   3: real-only->cat+coff
// EPI 4: mag/pha packed w<65 -> o1,o2
template<int EPI>
__global__ __launch_bounds__(256, 1)
void k_lmulT(const float2* __restrict__ A, const float2* __restrict__ in,
             float* __restrict__ o1, float* __restrict__ o2, int coff) {
    __shared__ float2 Ssh[32*128];   // [j][h] A-row strip
    __shared__ float2 Tch[32*128];   // [h][w] T chunk
    int p  = blockIdx.y;
    int j0 = blockIdx.x << 5;
    int t  = threadIdx.x;
    const float2* T = in + ((long)p << 14);
    {   // stage A strip: rows j0..j0+31 are contiguous in global
        const float4* Ag = (const float4*)(A + ((long)j0 << 7));
        float4* Sd = (float4*)Ssh;
        for (int i = t; i < 2048; i += 256) Sd[i] = Ag[i];
    }
    float2 acc[4][4] = {};
    int cq = t & 31, rp = t >> 5;
    for (int kc = 0; kc < 128; kc += 32) {
        __syncthreads();
        {
            const float4* Tg = (const float4*)(T + (kc << 7));
            float4* Td = (float4*)Tch;
            for (int i = t; i < 2048; i += 256) Td[i] = Tg[i];
        }
        __syncthreads();
#pragma unroll
        for (int kk = 0; kk < 32; ++kk) {
            int k = kc + kk;
            float2 s[4], m[4];
#pragma unroll
            for (int i = 0; i < 4; ++i) s[i] = Ssh[(((rp<<2)+i) << 7) + k];
#pragma unroll
            for (int q = 0; q < 4; ++q) m[q] = Tch[(kk << 7) + cq + (q<<5)];
#pragma unroll
            for (int i = 0; i < 4; ++i)
#pragma unroll
                for (int q = 0; q < 4; ++q) {
                    if (EPI == 3) {
                        acc[i][q].x = fmaf(s[i].x, m[q].x, acc[i][q].x);
                        acc[i][q].x = fmaf(-s[i].y, m[q].y, acc[i][q].x);
                    } else {
                        acc[i][q].x = fmaf(s[i].x, m[q].x, acc[i][q].x);
                        acc[i][q].x = fmaf(-s[i].y, m[q].y, acc[i][q].x);
                        acc[i][q].y = fmaf(s[i].x, m[q].y, acc[i][q].y);
                        acc[i][q].y = fmaf(s[i].y, m[q].x, acc[i][q].y);
                    }
                }
        }
    }
#pragma unroll
    for (int i = 0; i < 4; ++i) {
#pragma unroll
        for (int q = 0; q < 4; ++q) {
            int jj = j0 + (rp<<2) + i;
            int ww = cq + (q<<5);
            float2 v = acc[i][q];
            if (EPI == 1) {
                long idx = ((long)p << 14) + ((long)jj << 7) + ww;
                o1[idx] = sqrtf(v.x*v.x + v.y*v.y);
                o2[idx] = atan2f(v.y, v.x);
            } else if (EPI == 2) {
                int n = p >> 4, c = p & 15;
                o1[((long)(n*48 + coff + c) << 14) + ((long)jj << 7) + ww] = sqrtf(v.x*v.x + v.y*v.y);
            } else if (EPI == 3) {
                int n = p >> 4, c = p & 15;
                o1[((long)(n*48 + coff + c) << 14) + ((long)jj << 7) + ww] = v.x;
            } else if (EPI == 4) {
                if (ww < 65) {
                    long idx = (long)p*8320 + jj*65 + ww;
                    o1[idx] = sqrtf(v.x*v.x + v.y*v.y);
                    o2[idx] = atan2f(v.y, v.x);
                }
            }
        }
    }
}

// ---------------- wave-level 1x1 conv (float2 lanes, 128-spatial tiles) ------
template<int CIN, int COUT, int KSPLIT, int OSPLIT>
__global__ __launch_bounds__(256, 1)
void k_wconv(const float* __restrict__ in, const float* __restrict__ wgt,
             const float* __restrict__ bias, float* __restrict__ out,
             int S, int Ctin, int cstart, int Ctout, int costart) {
    constexpr int OW = COUT / OSPLIT;
    constexpr int KC = CIN / KSPLIT;
    constexpr int RSZ = (KSPLIT > 1) ? KSPLIT * COUT * 128 : 1;
    __shared__ float red[RSZ];
    int t = threadIdx.x, lane = t & 63;
    int wv = __builtin_amdgcn_readfirstlane(t >> 6);
    int oq = wv / KSPLIT, kq = wv % KSPLIT;
    int n = blockIdx.y, s0 = blockIdx.x << 7;
    const float* inb = in + ((long)(n*Ctin + cstart + kq*KC))*S + s0 + (lane<<1);
    const float* wb  = wgt + (oq*OW)*CIN + kq*KC;
    float2 acc[OW];
#pragma unroll
    for (int j = 0; j < OW; ++j) acc[j] = make_float2(0.f, 0.f);
#pragma unroll 4
    for (int c = 0; c < KC; ++c) {
        float2 xv = *(const float2*)(inb + (long)c*S);
#pragma unroll
        for (int j = 0; j < OW; ++j) {
            float w = wb[j*CIN + c];
            acc[j].x = fmaf(w, xv.x, acc[j].x);
            acc[j].y = fmaf(w, xv.y, acc[j].y);
        }
    }
    if (KSPLIT == 1) {
#pragma unroll
        for (int j = 0; j < OW; ++j) {
            int o = oq*OW + j;
            float b = bias ? bias[o] : 0.f;
            *(float2*)(out + ((long)(n*Ctout + costart + o))*S + s0 + (lane<<1))
                = make_float2(acc[j].x + b, acc[j].y + b);
        }
    } else {
#pragma unroll
        for (int j = 0; j < OW; ++j) {
            int o = oq*OW + j;
            *(float2*)&red[((kq*COUT + o) << 7) + (lane<<1)] = acc[j];
        }
        __syncthreads();
        for (int idx = t; idx < COUT*64; idx += 256) {
            int o = idx >> 6, l2 = (idx & 63) << 1;
            float b = bias ? bias[o] : 0.f;
            float2 v = make_float2(b, b);
#pragma unroll
            for (int k2 = 0; k2 < KSPLIT; ++k2) {
                float2 r = *(const float2*)&red[((k2*COUT + o) << 7) + l2];
                v.x += r.x; v.y += r.y;
            }
            *(float2*)(out + ((long)(n*Ctout + costart + o))*S + s0 + l2) = v;
        }
    }
}

// ---------------- maskconv: LDS-tiled, branchless 3x3 ------------------------
__global__ __launch_bounds__(256, 2)
void k_maskconv2(const float* __restrict__ mag, const float* __restrict__ ws3,
                 const float* __restrict__ bs, const float* __restrict__ wf,
                 const float* __restrict__ bf, float* __restrict__ out) {
    __shared__ float patch[16][324];   // 18x18 per channel, mask1 applied
    int n = blockIdx.y;
    int h0 = (blockIdx.x >> 3) << 4, w0 = (blockIdx.x & 7) << 4;
    int t = threadIdx.x;
    const float* magn = mag + ((long)n << 18);
    for (int idx = t; idx < 16*324; idx += 256) {
        int c = idx / 324, r = idx - c*324;
        int ph = r / 18, pw = r - ph*18;
        int gh = h0 - 1 + ph, gw = w0 - 1 + pw;
        float v = 0.f;
        if (gh >= 19 && gh < 109 && gw >= 19 && gw < 109)
            v = magn[(c<<14) + (gh<<7) + gw];
        patch[c][r] = v;
    }
    __syncthreads();
    int ty = t >> 4, tx = t & 15;
    int h = h0 + ty, w = w0 + tx;
    bool in1 = (h >= 19 && h < 109 && w >= 19 && w < 109);
    unsigned long long bal = __ballot(in1);
    float res[16];
    if (bal != 0ull) {
        float acc[16];
#pragma unroll
        for (int o = 0; o < 16; ++o) acc[o] = bs[o];
        for (int c = 0; c < 16; ++c) {
            float tap[9];
#pragma unroll
            for (int dh = 0; dh < 3; ++dh)
#pragma unroll
                for (int dw = 0; dw < 3; ++dw)
                    tap[dh*3+dw] = patch[c][(ty+dh)*18 + tx+dw];
            const float* wp = ws3 + c*9;
#pragma unroll
            for (int o = 0; o < 16; ++o)
#pragma unroll
                for (int k = 0; k < 9; ++k)
                    acc[o] = fmaf(wp[o*144 + k], tap[k], acc[o]);
        }
#pragma unroll
        for (int o = 0; o < 16; ++o) res[o] = acc[o];
    }
    if (bal != ~0ull) {
        float xv[16];
#pragma unroll
        for (int c = 0; c < 16; ++c) xv[c] = magn[(c<<14) + (h<<7) + w];
#pragma unroll
        for (int o = 0; o < 16; ++o) {
            float a = bf[o];
#pragma unroll
            for (int c = 0; c < 16; ++c) a = fmaf(wf[o*16 + c], xv[c], a);
            if (!in1) res[o] = a;
        }
    }
#pragma unroll
    for (int o = 0; o < 16; ++o)
        out[((long)((n<<4) + o) << 14) + (h << 7) + w] = res[o];
}

// ---------------- launch ----------------------------------------------------
extern "C" void kernel_launch(void* const* d_in, const int* in_sizes, int n_in,
                              void* d_out, int out_size, void* d_ws, size_t ws_size,
                              hipStream_t stream) {
    (void)in_sizes; (void)n_in; (void)out_size; (void)d_ws; (void)ws_size;
    const float* x        = (const float*)d_in[0];
    const float* conv1_w  = (const float*)d_in[1];
    const float* mag_s_w  = (const float*)d_in[2];
    const float* mag_s_b  = (const float*)d_in[3];
    const float* mag_f_w  = (const float*)d_in[4];
    const float* mag_f_b  = (const float*)d_in[5];
    const float* mag_w_   = (const float*)d_in[6];
    const float* mag_b_   = (const float*)d_in[7];
    const float* pha_w_   = (const float*)d_in[8];
    const float* pha_b_   = (const float*)d_in[9];
    const float* conv_0_w = (const float*)d_in[10];
    const float* conv_0_b = (const float*)d_in[11];
    const float* conv_1_w = (const float*)d_in[12];
    const float* conv_1_b = (const float*)d_in[13];
    const float* conv2_w  = (const float*)d_in[14];
    float* outp = (float*)d_out;

    float2 *Mf, *MfT, *Mb, *MbT, *Fm, *IFm, *bufA;
    float *x1, *mag, *pha, *t1, *t2, *cat;
    hipGetSymbolAddress((void**)&Mf,   HIP_SYMBOL(g_Mf));
    hipGetSymbolAddress((void**)&MfT,  HIP_SYMBOL(g_MfT));
    hipGetSymbolAddress((void**)&Mb,   HIP_SYMBOL(g_Mb));
    hipGetSymbolAddress((void**)&MbT,  HIP_SYMBOL(g_MbT));
    hipGetSymbolAddress((void**)&Fm,   HIP_SYMBOL(g_F));
    hipGetSymbolAddress((void**)&IFm,  HIP_SYMBOL(g_IF));
    hipGetSymbolAddress((void**)&bufA, HIP_SYMBOL(g_bufA));
    hipGetSymbolAddress((void**)&x1,   HIP_SYMBOL(g_x1));
    hipGetSymbolAddress((void**)&mag,  HIP_SYMBOL(g_mag));
    hipGetSymbolAddress((void**)&pha,  HIP_SYMBOL(g_pha));
    hipGetSymbolAddress((void**)&t1,   HIP_SYMBOL(g_t1));
    hipGetSymbolAddress((void**)&t2,   HIP_SYMBOL(g_t2));
    hipGetSymbolAddress((void**)&cat,  HIP_SYMBOL(g_cat));

    dim3 gT(4, 64), bt(256, 1, 1);

    // matrices (incl. transposed forms for the rmul resident side)
    k_build_M05f<<<256, 64, 0, stream>>>();
    k_build_Mbf <<<256, 64, 0, stream>>>();
    k_build_Ff  <<<256, 64, 0, stream>>>();

    // x1 = 1x1 conv (192 -> 48)
    k_wconv<192,48,2,2><<<dim3(128,4), 256, 0, stream>>>(x, conv1_w, nullptr, x1, 16384, 192, 0, 48, 0);

    // FRFT forward on x_05 (ch 16..31): Fre = Mf X Mf^T; fused mag/pha
    k_rmulT<1><<<gT, bt, 0, stream>>>(MfT, x1, nullptr, nullptr, bufA, 48, 16, 16);
    k_lmulT<1><<<gT, bt, 0, stream>>>(Mf, bufA, mag, pha, 0);

    // masked convs + channel mixes
    k_maskconv2<<<dim3(64,4), 256, 0, stream>>>(mag, mag_s_w, mag_s_b, mag_f_w, mag_f_b, t1);
    k_wconv<16,16,2,2><<<dim3(128,4), 256, 0, stream>>>(t1,  mag_w_, mag_b_, t2, 16384, 16, 0, 16, 0);
    k_wconv<16,16,2,2><<<dim3(128,4), 256, 0, stream>>>(pha, pha_w_, pha_b_, t1, 16384, 16, 0, 16, 0);

    // FRFT backward (combine fused into loader): |Mb Y Mb^T| -> cat ch 16..31
    k_rmulT<2><<<gT, bt, 0, stream>>>(MbT, nullptr, t2, t1, bufA, 0, 0, 0);
    k_lmulT<2><<<gT, bt, 0, stream>>>(Mb, bufA, cat, nullptr, 16);

    // FFT branch on x_1 (ch 32..47): G = F X F^T; fused packed mag/pha
    k_rmulT<1><<<gT, bt, 0, stream>>>(Fm, x1, nullptr, nullptr, bufA, 48, 16, 32);
    k_lmulT<4><<<gT, bt, 0, stream>>>(Fm, bufA, mag, pha, 0);
    k_wconv<16,16,2,2><<<dim3(65,4), 256, 0, stream>>>(mag, conv_1_w, conv_1_b, t1, 8320, 16, 0, 16, 0);
    k_wconv<16,16,2,2><<<dim3(65,4), 256, 0, stream>>>(pha, conv_1_w, conv_1_b, t2, 8320, 16, 0, 16, 0);
    // inverse rfft2 (combine65 + Hermitian extension fused into loader)
    k_rmulT<3><<<gT, bt, 0, stream>>>(IFm, nullptr, t1, t2, bufA, 0, 0, 0);
    k_lmulT<3><<<gT, bt, 0, stream>>>(IFm, bufA, cat, nullptr, 32);

    // x_0o -> cat ch 0..15
    k_wconv<16,16,2,2><<<dim3(128,4), 256, 0, stream>>>(x1, conv_0_w, conv_0_b, cat, 16384, 48, 0, 48, 0);

    // final 1x1 conv (48 -> 192)
    k_wconv<48,192,1,4><<<dim3(128,4), 256, 0, stream>>>(cat, conv2_w, nullptr, outp, 16384, 48, 0, 192, 0);
}

// Round 8
// 399.452 us; speedup vs baseline: 1.4088x; 1.0854x over previous
//
#include <hip/hip_runtime.h>
#include <math.h>

#define PI_D 3.14159265358979323846
#define TWO_PI_F 6.2831853071795864f

// ---------------- persistent device buffers ---------------------------------
__device__ __align__(16) float2 g_Mf [128*128];
__device__ __align__(16) float2 g_MfT[128*128];
__device__ __align__(16) float2 g_Mb [128*128];
__device__ __align__(16) float2 g_MbT[128*128];
__device__ __align__(16) float2 g_F  [128*128];   // symmetric
__device__ __align__(16) float2 g_IF [128*128];   // symmetric
__device__ __align__(16) float  g_x1 [4*48*16384];
__device__ __align__(16) float2 g_bufA[64*16384];
__device__ __align__(16) float  g_mag[64*16384];
__device__ __align__(16) float  g_pha[64*16384];
__device__ __align__(16) float  g_t1 [64*16384];
__device__ __align__(16) float  g_t2 [64*16384];
__device__ __align__(16) float  g_cat[4*48*16384];

// ---------------- matrix builders -------------------------------------------
// M05 (+ transposed) and the DFT matrices in one kernel.
__global__ void k_build_A() {
    int tid = blockIdx.x*blockDim.x + threadIdx.x;
    if (tid >= 128*128) return;
    int o = tid >> 7, m = tid & 127;
    const double chc = -PI_D/128.0 * tan(PI_D/8.0) * 0.25;
    const double c   =  PI_D/(512.0*sin(PI_D/4.0));
    const double inv2pi = 1.0/(2.0*PI_D);
    float sr, si;
    {   // q = 2m term (sinc = 1)
        int n1 = 2*m - 127, tt = 2*(o - m);
        double ang = chc*(double)(n1*n1) + c*(double)(tt*tt);
        double r = ang*inv2pi; r -= floor(r);
        float af = (float)(r*2.0*PI_D);
        float sn, cs; __sincosf(af, &sn, &cs);
        sr = cs; si = sn;
    }
    for (int j = 0; j < 127; ++j) {
        int q  = 2*j + 1;
        int n1 = q - 127, tt = 2*o - q, d = q - 2*m;
        double ang = chc*(double)(n1*n1) + c*(double)(tt*tt);
        double r = ang*inv2pi; r -= floor(r);
        float af = (float)(r*2.0*PI_D);
        float s = (((d-1)>>1) & 1) ? -2.0f : 2.0f;
        s /= (3.14159265358979f*(float)d);
        float sn, cs; __sincosf(af, &sn, &cs);
        sr += s*cs; si += s*sn;
    }
    int n2 = 2*o - 127;
    double ph = chc*(double)(n2*n2) - PI_D/8.0;
    double r = ph*inv2pi; r -= floor(r);
    float pf = (float)(r*2.0*PI_D);
    float scale = (float)sqrt(c/PI_D);
    float sn, cs; __sincosf(pf, &sn, &cs);
    float cr = cs*scale, ci = sn*scale;
    float2 v = make_float2(sr*cr - si*ci, sr*ci + si*cr);
    g_Mf[tid] = v;
    g_MfT[(m<<7) + o] = v;
    // DFT matrices (independent)
    int p = (o*m) & 127;
    float ang2 = TWO_PI_F*(float)p/128.0f;
    float sn2, cs2; __sincosf(ang2, &sn2, &cs2);
    g_F[tid]  = make_float2(cs2, -sn2);
    g_IF[tid] = make_float2(cs2*0.0078125f, sn2*0.0078125f);
}

__global__ void k_build_Mbf() {
    __shared__ float2 W[128];
    int t = threadIdx.x;
    for (int i = t; i < 128; i += 64) {
        float ang = TWO_PI_F*(float)i/128.0f;
        float sn, cs; sincosf(ang, &sn, &cs);
        float invs = 0.08838834764831845f;
        W[i] = make_float2(cs*invs, sn*invs);
    }
    __syncthreads();
    int tid = blockIdx.x*blockDim.x + t;
    if (tid >= 128*128) return;
    int o = tid >> 7, m = tid & 127;
    float sr = 0.f, si = 0.f;
    for (int r = 0; r < 128; ++r) {
        float2 a = g_Mf[(o<<7) + r];
        int k = ((r+64)*(m+64)) & 127;
        float2 w = W[k];
        sr += a.x*w.x - a.y*w.y;
        si += a.x*w.y + a.y*w.x;
    }
    float2 v = make_float2(sr, si);
    g_Mb[tid] = v;
    g_MbT[(m<<7) + o] = v;
}

// ---------------- stream loaders (rmul T-side) -------------------------------
// LM 1: real from x1 slice  2: mag/pha full plane  3: mag/pha packed65 + Hermitian
template<int LM>
__device__ inline void load_T4(float2* tr, const float* mp, const float* pp,
                               const float* Trl, int hh, int w4) {
    if (LM == 1) {
        float4 v = *(const float4*)(Trl + (hh<<7) + w4);
        tr[0] = make_float2(v.x, 0.f); tr[1] = make_float2(v.y, 0.f);
        tr[2] = make_float2(v.z, 0.f); tr[3] = make_float2(v.w, 0.f);
    } else if (LM == 2) {
#pragma unroll
        for (int i = 0; i < 4; ++i) {
            int idx = (hh<<7) + w4 + i;
            float m = mp[idx], ph = pp[idx];
            float sn, cs; __sincosf(ph, &sn, &cs);
            tr[i] = make_float2(m*cs, m*sn);
        }
    } else {
#pragma unroll
        for (int i = 0; i < 4; ++i) {
            int w = w4 + i;
            int h2 = hh, w2 = w; float sg = 1.f;
            if (w >= 65) { h2 = (128 - hh) & 127; w2 = 128 - w; sg = -1.f; }
            int idx = h2*65 + w2;
            float m = mp[idx], ph = pp[idx];
            float sn, cs; __sincosf(ph, &sn, &cs);
            tr[i] = make_float2(m*cs, sg*m*sn);
        }
    }
}

// ---------------- rmul: out[p,h,j] = sum_w T[p,h,w] * A[j,w] -----------------
// MT = A transposed [w][j]; 16-row stream strip resident, MT chunked (32 k).
template<int LM>
__global__ __launch_bounds__(256, 2)
void k_rmulT(const float2* __restrict__ MT, const float* __restrict__ Trl,
             const float* __restrict__ mp_, const float* __restrict__ pp_,
             float2* __restrict__ out, int Ctot, int Csub, int cstart) {
    constexpr bool RS = (LM == 1);
    __shared__ float2 Ssh[16*128];   // [r][k]  stream strip (16 KB)
    __shared__ float2 Mch[32*128];   // [k][j]  resident chunk (32 KB)
    int p  = blockIdx.y;
    int r0 = blockIdx.x << 4;
    int t  = threadIdx.x;
    const float* Trp = nullptr; const float* mp = nullptr; const float* pp = nullptr;
    if (LM == 1) { int n = p / Csub, c = p - n*Csub; Trp = Trl + ((long)(n*Ctot + cstart + c) << 14); }
    if (LM == 2) { mp = mp_ + ((long)p << 14); pp = pp_ + ((long)p << 14); }
    if (LM == 3) { mp = mp_ + (long)p*8320;   pp = pp_ + (long)p*8320; }
    // stage stream strip (16 rows x 128 k)
    for (int u = t; u < 512; u += 256) {
        int row = u >> 5, w4 = (u & 31) << 2;
        float2 tr4[4];
        load_T4<LM>(tr4, mp, pp, Trp, r0 + row, w4);
        float4* d = (float4*)&Ssh[(row << 7) + w4];
        d[0] = make_float4(tr4[0].x, tr4[0].y, tr4[1].x, tr4[1].y);
        d[1] = make_float4(tr4[2].x, tr4[2].y, tr4[3].x, tr4[3].y);
    }
    float2 acc[4][2] = {};
    int cq = t & 63, rp = t >> 6;      // rows 4rp..4rp+3, cols cq, cq+64
    for (int kc = 0; kc < 128; kc += 32) {
        __syncthreads();
        {
            const float4* Mg = (const float4*)(MT + (kc << 7));
            float4* Md = (float4*)Mch;
            for (int i = t; i < 2048; i += 256) Md[i] = Mg[i];
        }
        __syncthreads();
#pragma unroll
        for (int kk = 0; kk < 32; ++kk) {
            int k = kc + kk;
            float2 s[4], m[2];
#pragma unroll
            for (int i = 0; i < 4; ++i) s[i] = Ssh[(((rp<<2)+i) << 7) + k];
            m[0] = Mch[(kk << 7) + cq];
            m[1] = Mch[(kk << 7) + cq + 64];
#pragma unroll
            for (int i = 0; i < 4; ++i)
#pragma unroll
                for (int q = 0; q < 2; ++q) {
                    if (RS) {
                        acc[i][q].x = fmaf(s[i].x, m[q].x, acc[i][q].x);
                        acc[i][q].y = fmaf(s[i].x, m[q].y, acc[i][q].y);
                    } else {
                        acc[i][q].x = fmaf(s[i].x, m[q].x, acc[i][q].x);
                        acc[i][q].x = fmaf(-s[i].y, m[q].y, acc[i][q].x);
                        acc[i][q].y = fmaf(s[i].x, m[q].y, acc[i][q].y);
                        acc[i][q].y = fmaf(s[i].y, m[q].x, acc[i][q].y);
                    }
                }
        }
    }
    long base = ((long)p << 14);
#pragma unroll
    for (int i = 0; i < 4; ++i) {
        out[base + ((long)(r0 + (rp<<2) + i) << 7) + cq]      = acc[i][0];
        out[base + ((long)(r0 + (rp<<2) + i) << 7) + cq + 64] = acc[i][1];
    }
}

// ---------------- lmul: out[p,j,w] = sum_h A[j,h] * T[p,h,w] -----------------
// Stream = 16 A-rows; resident = T plane chunked (32 h). Fused epilogues:
// EPI 1: mag/pha full -> o1,o2   2: abs->cat+coff   3: real-only->cat+coff
// EPI 4: mag/pha packed w<65 -> o1,o2
template<int EPI>
__global__ __launch_bounds__(256, 2)
void k_lmulT(const float2* __restrict__ A, const float2* __restrict__ in,
             float* __restrict__ o1, float* __restrict__ o2, int coff) {
    __shared__ float2 Ssh[16*128];   // [j][h]
    __shared__ float2 Tch[32*128];   // [h][w]
    int p  = blockIdx.y;
    int j0 = blockIdx.x << 4;
    int t  = threadIdx.x;
    const float2* T = in + ((long)p << 14);
    {
        const float4* Ag = (const float4*)(A + ((long)j0 << 7));
        float4* Sd = (float4*)Ssh;
        for (int i = t; i < 1024; i += 256) Sd[i] = Ag[i];
    }
    float2 acc[4][2] = {};
    int cq = t & 63, rp = t >> 6;
    for (int kc = 0; kc < 128; kc += 32) {
        __syncthreads();
        {
            const float4* Tg = (const float4*)(T + (kc << 7));
            float4* Td = (float4*)Tch;
            for (int i = t; i < 2048; i += 256) Td[i] = Tg[i];
        }
        __syncthreads();
#pragma unroll
        for (int kk = 0; kk < 32; ++kk) {
            int k = kc + kk;
            float2 s[4], m[2];
#pragma unroll
            for (int i = 0; i < 4; ++i) s[i] = Ssh[(((rp<<2)+i) << 7) + k];
            m[0] = Tch[(kk << 7) + cq];
            m[1] = Tch[(kk << 7) + cq + 64];
#pragma unroll
            for (int i = 0; i < 4; ++i)
#pragma unroll
                for (int q = 0; q < 2; ++q) {
                    if (EPI == 3) {
                        acc[i][q].x = fmaf(s[i].x, m[q].x, acc[i][q].x);
                        acc[i][q].x = fmaf(-s[i].y, m[q].y, acc[i][q].x);
                    } else {
                        acc[i][q].x = fmaf(s[i].x, m[q].x, acc[i][q].x);
                        acc[i][q].x = fmaf(-s[i].y, m[q].y, acc[i][q].x);
                        acc[i][q].y = fmaf(s[i].x, m[q].y, acc[i][q].y);
                        acc[i][q].y = fmaf(s[i].y, m[q].x, acc[i][q].y);
                    }
                }
        }
    }
#pragma unroll
    for (int i = 0; i < 4; ++i) {
#pragma unroll
        for (int q = 0; q < 2; ++q) {
            int jj = j0 + (rp<<2) + i;
            int ww = cq + (q<<6);
            float2 v = acc[i][q];
            if (EPI == 1) {
                long idx = ((long)p << 14) + ((long)jj << 7) + ww;
                o1[idx] = sqrtf(v.x*v.x + v.y*v.y);
                o2[idx] = atan2f(v.y, v.x);
            } else if (EPI == 2) {
                int n = p >> 4, c = p & 15;
                o1[((long)(n*48 + coff + c) << 14) + ((long)jj << 7) + ww] = sqrtf(v.x*v.x + v.y*v.y);
            } else if (EPI == 3) {
                int n = p >> 4, c = p & 15;
                o1[((long)(n*48 + coff + c) << 14) + ((long)jj << 7) + ww] = v.x;
            } else if (EPI == 4) {
                if (ww < 65) {
                    long idx = (long)p*8320 + jj*65 + ww;
                    o1[idx] = sqrtf(v.x*v.x + v.y*v.y);
                    o2[idx] = atan2f(v.y, v.x);
                }
            }
        }
    }
}

// ---------------- wave-level 1x1 conv (float2 lanes, 128-spatial tiles) ------
template<int CIN, int COUT, int KSPLIT, int OSPLIT>
__global__ __launch_bounds__(256, 1)
void k_wconv(const float* __restrict__ in, const float* __restrict__ wgt,
             const float* __restrict__ bias, float* __restrict__ out,
             int S, int Ctin, int cstart, int Ctout, int costart) {
    constexpr int OW = COUT / OSPLIT;
    constexpr int KC = CIN / KSPLIT;
    constexpr int RSZ = (KSPLIT > 1) ? KSPLIT * COUT * 128 : 1;
    __shared__ float red[RSZ];
    int t = threadIdx.x, lane = t & 63;
    int wv = __builtin_amdgcn_readfirstlane(t >> 6);
    int oq = wv / KSPLIT, kq = wv % KSPLIT;
    int n = blockIdx.y, s0 = blockIdx.x << 7;
    const float* inb = in + ((long)(n*Ctin + cstart + kq*KC))*S + s0 + (lane<<1);
    const float* wb  = wgt + (oq*OW)*CIN + kq*KC;
    float2 acc[OW];
#pragma unroll
    for (int j = 0; j < OW; ++j) acc[j] = make_float2(0.f, 0.f);
#pragma unroll 4
    for (int c = 0; c < KC; ++c) {
        float2 xv = *(const float2*)(inb + (long)c*S);
#pragma unroll
        for (int j = 0; j < OW; ++j) {
            float w = wb[j*CIN + c];
            acc[j].x = fmaf(w, xv.x, acc[j].x);
            acc[j].y = fmaf(w, xv.y, acc[j].y);
        }
    }
    if (KSPLIT == 1) {
#pragma unroll
        for (int j = 0; j < OW; ++j) {
            int o = oq*OW + j;
            float b = bias ? bias[o] : 0.f;
            *(float2*)(out + ((long)(n*Ctout + costart + o))*S + s0 + (lane<<1))
                = make_float2(acc[j].x + b, acc[j].y + b);
        }
    } else {
#pragma unroll
        for (int j = 0; j < OW; ++j) {
            int o = oq*OW + j;
            *(float2*)&red[((kq*COUT + o) << 7) + (lane<<1)] = acc[j];
        }
        __syncthreads();
        for (int idx = t; idx < COUT*64; idx += 256) {
            int o = idx >> 6, l2 = (idx & 63) << 1;
            float b = bias ? bias[o] : 0.f;
            float2 v = make_float2(b, b);
#pragma unroll
            for (int k2 = 0; k2 < KSPLIT; ++k2) {
                float2 r = *(const float2*)&red[((k2*COUT + o) << 7) + l2];
                v.x += r.x; v.y += r.y;
            }
            *(float2*)(out + ((long)(n*Ctout + costart + o))*S + s0 + l2) = v;
        }
    }
}

// ---------------- 16->16 channel-mix, two jobs selected by blockIdx.z --------
__device__ inline void mix16(const float* __restrict__ in, const float* __restrict__ w,
                             const float* __restrict__ b, float* __restrict__ out,
                             int Ctin, int cstart, int Ctout, int costart, int S) {
    int t = threadIdx.x, lane = t & 63;
    int oq = __builtin_amdgcn_readfirstlane(t >> 6);   // 4 outputs per wave
    int n = blockIdx.y, s0 = blockIdx.x << 7;
    const float* inb = in + ((long)(n*Ctin + cstart))*S + s0 + (lane<<1);
    float2 xv[16];
#pragma unroll
    for (int c = 0; c < 16; ++c) xv[c] = *(const float2*)(inb + (long)c*S);
#pragma unroll
    for (int j = 0; j < 4; ++j) {
        int o = oq*4 + j;
        float bb = b ? b[o] : 0.f;
        float2 a = make_float2(bb, bb);
#pragma unroll
        for (int c = 0; c < 16; ++c) {
            float ww = w[o*16 + c];
            a.x = fmaf(ww, xv[c].x, a.x);
            a.y = fmaf(ww, xv[c].y, a.y);
        }
        *(float2*)(out + ((long)(n*Ctout + costart + o))*S + s0 + (lane<<1)) = a;
    }
}

__global__ __launch_bounds__(256, 2)
void k_mix2(const float* inA, const float* wA, const float* bA, float* outA,
            int CtinA, int cstartA, int CtoutA, int costartA,
            const float* inB, const float* wB, const float* bB, float* outB,
            int CtinB, int cstartB, int CtoutB, int costartB, int S) {
    if (blockIdx.z == 0)
        mix16(inA, wA, bA, outA, CtinA, cstartA, CtoutA, costartA, S);
    else
        mix16(inB, wB, bB, outB, CtinB, cstartB, CtoutB, costartB, S);
}

// ---------------- maskconv + fused mag channel-mix ---------------------------
__global__ __launch_bounds__(256, 2)
void k_maskconv3(const float* __restrict__ mag, const float* __restrict__ ws3,
                 const float* __restrict__ bs, const float* __restrict__ wf,
                 const float* __restrict__ bf, const float* __restrict__ wm,
                 const float* __restrict__ bm, float* __restrict__ out) {
    __shared__ float patch[16][324];   // 18x18 per channel, mask1 applied
    int n = blockIdx.y;
    int h0 = (blockIdx.x >> 3) << 4, w0 = (blockIdx.x & 7) << 4;
    int t = threadIdx.x;
    const float* magn = mag + ((long)n << 18);
    for (int idx = t; idx < 16*324; idx += 256) {
        int c = idx / 324, r = idx - c*324;
        int ph = r / 18, pw = r - ph*18;
        int gh = h0 - 1 + ph, gw = w0 - 1 + pw;
        float v = 0.f;
        if (gh >= 19 && gh < 109 && gw >= 19 && gw < 109)
            v = magn[(c<<14) + (gh<<7) + gw];
        patch[c][r] = v;
    }
    __syncthreads();
    int ty = t >> 4, tx = t & 15;
    int h = h0 + ty, w = w0 + tx;
    bool in1 = (h >= 19 && h < 109 && w >= 19 && w < 109);
    unsigned long long bal = __ballot(in1);
    float res[16];
    if (bal != 0ull) {
        float acc[16];
#pragma unroll
        for (int o = 0; o < 16; ++o) acc[o] = bs[o];
        for (int c = 0; c < 16; ++c) {
            float tap[9];
#pragma unroll
            for (int dh = 0; dh < 3; ++dh)
#pragma unroll
                for (int dw = 0; dw < 3; ++dw)
                    tap[dh*3+dw] = patch[c][(ty+dh)*18 + tx+dw];
            const float* wp = ws3 + c*9;
#pragma unroll
            for (int o = 0; o < 16; ++o)
#pragma unroll
                for (int k = 0; k < 9; ++k)
                    acc[o] = fmaf(wp[o*144 + k], tap[k], acc[o]);
        }
#pragma unroll
        for (int o = 0; o < 16; ++o) res[o] = acc[o];
    }
    if (bal != ~0ull) {
        float xv[16];
#pragma unroll
        for (int c = 0; c < 16; ++c) xv[c] = magn[(c<<14) + (h<<7) + w];
#pragma unroll
        for (int o = 0; o < 16; ++o) {
            float a = bf[o];
#pragma unroll
            for (int c = 0; c < 16; ++c) a = fmaf(wf[o*16 + c], xv[c], a);
            if (!in1) res[o] = a;
        }
    }
    // fused channel mix: out[o2] = bm[o2] + sum_o wm[o2,o]*res[o]
#pragma unroll
    for (int o2 = 0; o2 < 16; ++o2) {
        float a = bm[o2];
#pragma unroll
        for (int o = 0; o < 16; ++o)
            a = fmaf(wm[o2*16 + o], res[o], a);
        out[((long)((n<<4) + o2) << 14) + (h << 7) + w] = a;
    }
}

// ---------------- launch ----------------------------------------------------
extern "C" void kernel_launch(void* const* d_in, const int* in_sizes, int n_in,
                              void* d_out, int out_size, void* d_ws, size_t ws_size,
                              hipStream_t stream) {
    (void)in_sizes; (void)n_in; (void)out_size; (void)d_ws; (void)ws_size;
    const float* x        = (const float*)d_in[0];
    const float* conv1_w  = (const float*)d_in[1];
    const float* mag_s_w  = (const float*)d_in[2];
    const float* mag_s_b  = (const float*)d_in[3];
    const float* mag_f_w  = (const float*)d_in[4];
    const float* mag_f_b  = (const float*)d_in[5];
    const float* mag_w_   = (const float*)d_in[6];
    const float* mag_b_   = (const float*)d_in[7];
    const float* pha_w_   = (const float*)d_in[8];
    const float* pha_b_   = (const float*)d_in[9];
    const float* conv_0_w = (const float*)d_in[10];
    const float* conv_0_b = (const float*)d_in[11];
    const float* conv_1_w = (const float*)d_in[12];
    const float* conv_1_b = (const float*)d_in[13];
    const float* conv2_w  = (const float*)d_in[14];
    float* outp = (float*)d_out;

    float2 *Mf, *MfT, *Mb, *MbT, *Fm, *IFm, *bufA;
    float *x1, *mag, *pha, *t1, *t2, *cat;
    hipGetSymbolAddress((void**)&Mf,   HIP_SYMBOL(g_Mf));
    hipGetSymbolAddress((void**)&MfT,  HIP_SYMBOL(g_MfT));
    hipGetSymbolAddress((void**)&Mb,   HIP_SYMBOL(g_Mb));
    hipGetSymbolAddress((void**)&MbT,  HIP_SYMBOL(g_MbT));
    hipGetSymbolAddress((void**)&Fm,   HIP_SYMBOL(g_F));
    hipGetSymbolAddress((void**)&IFm,  HIP_SYMBOL(g_IF));
    hipGetSymbolAddress((void**)&bufA, HIP_SYMBOL(g_bufA));
    hipGetSymbolAddress((void**)&x1,   HIP_SYMBOL(g_x1));
    hipGetSymbolAddress((void**)&mag,  HIP_SYMBOL(g_mag));
    hipGetSymbolAddress((void**)&pha,  HIP_SYMBOL(g_pha));
    hipGetSymbolAddress((void**)&t1,   HIP_SYMBOL(g_t1));
    hipGetSymbolAddress((void**)&t2,   HIP_SYMBOL(g_t2));
    hipGetSymbolAddress((void**)&cat,  HIP_SYMBOL(g_cat));

    dim3 gT(8, 64), bt(256, 1, 1);

    // matrices
    k_build_A  <<<256, 64, 0, stream>>>();
    k_build_Mbf<<<256, 64, 0, stream>>>();

    // x1 = 1x1 conv (192 -> 48)
    k_wconv<192,48,2,2><<<dim3(128,4), 256, 0, stream>>>(x, conv1_w, nullptr, x1, 16384, 192, 0, 48, 0);

    // FRFT forward on x_05 (ch 16..31): Fre = Mf X Mf^T; fused mag/pha
    k_rmulT<1><<<gT, bt, 0, stream>>>(MfT, x1, nullptr, nullptr, bufA, 48, 16, 16);
    k_lmulT<1><<<gT, bt, 0, stream>>>(Mf, bufA, mag, pha, 0);

    // masked convs (+ fused mag channel mix) -> t2; pha mix + conv_0 union
    k_maskconv3<<<dim3(64,4), 256, 0, stream>>>(mag, mag_s_w, mag_s_b, mag_f_w, mag_f_b, mag_w_, mag_b_, t2);
    k_mix2<<<dim3(128,4,2), 256, 0, stream>>>(pha, pha_w_, pha_b_, t1, 16, 0, 16, 0,
                                              x1, conv_0_w, conv_0_b, cat, 48, 0, 48, 0, 16384);

    // FRFT backward (combine fused into loader): |Mb Y Mb^T| -> cat ch 16..31
    k_rmulT<2><<<gT, bt, 0, stream>>>(MbT, nullptr, t2, t1, bufA, 0, 0, 0);
    k_lmulT<2><<<gT, bt, 0, stream>>>(Mb, bufA, cat, nullptr, 16);

    // FFT branch on x_1 (ch 32..47): G = F X F^T; fused packed mag/pha
    k_rmulT<1><<<gT, bt, 0, stream>>>(Fm, x1, nullptr, nullptr, bufA, 48, 16, 32);
    k_lmulT<4><<<gT, bt, 0, stream>>>(Fm, bufA, mag, pha, 0);
    k_mix2<<<dim3(65,4,2), 256, 0, stream>>>(mag, conv_1_w, conv_1_b, t1, 16, 0, 16, 0,
                                             pha, conv_1_w, conv_1_b, t2, 16, 0, 16, 0, 8320);
    // inverse rfft2 (combine65 + Hermitian extension fused into loader)
    k_rmulT<3><<<gT, bt, 0, stream>>>(IFm, nullptr, t1, t2, bufA, 0, 0, 0);
    k_lmulT<3><<<gT, bt, 0, stream>>>(IFm, bufA, cat, nullptr, 32);

    // final 1x1 conv (48 -> 192)
    k_wconv<48,192,1,4><<<dim3(128,4), 256, 0, stream>>>(cat, conv2_w, nullptr, outp, 16384, 48, 0, 192, 0);
}

// Round 9
// 353.965 us; speedup vs baseline: 1.5899x; 1.1285x over previous
//
#include <hip/hip_runtime.h>
#include <math.h>

#define PI_D 3.14159265358979323846
#define TWO_PI_F 6.2831853071795864f

// ---------------- persistent device buffers ---------------------------------
__device__ __align__(16) float2 g_Mf [128*128];
__device__ __align__(16) float2 g_MfT[128*128];
__device__ __align__(16) float2 g_Mb [128*128];
__device__ __align__(16) float2 g_MbT[128*128];
__device__ __align__(16) float2 g_F  [128*128];   // symmetric
__device__ __align__(16) float2 g_IF [128*128];   // symmetric
__device__ __align__(16) float  g_x1 [4*48*16384];
__device__ __align__(16) float2 g_bufA[64*16384];
__device__ __align__(16) float2 g_bufB[64*16384];
__device__ __align__(16) float  g_mag[64*16384];
__device__ __align__(16) float  g_pha[64*16384];
__device__ __align__(16) float  g_m65[64*8320];
__device__ __align__(16) float  g_p65[64*8320];
__device__ __align__(16) float  g_t1 [64*16384];
__device__ __align__(16) float  g_t2 [64*16384];
__device__ __align__(16) float  g_t3 [64*8320];
__device__ __align__(16) float  g_t4 [64*8320];
__device__ __align__(16) float  g_cat[4*48*16384];

// ---------------- builder bodies ---------------------------------------------
__device__ inline void build_A_body(int tid) {
    if (tid >= 128*128) return;
    int o = tid >> 7, m = tid & 127;
    const double chc = -PI_D/128.0 * tan(PI_D/8.0) * 0.25;
    const double c   =  PI_D/(512.0*sin(PI_D/4.0));
    const double inv2pi = 1.0/(2.0*PI_D);
    float sr, si;
    {   // q = 2m term (sinc = 1)
        int n1 = 2*m - 127, tt = 2*(o - m);
        double ang = chc*(double)(n1*n1) + c*(double)(tt*tt);
        double r = ang*inv2pi; r -= floor(r);
        float af = (float)(r*2.0*PI_D);
        float sn, cs; __sincosf(af, &sn, &cs);
        sr = cs; si = sn;
    }
    for (int j = 0; j < 127; ++j) {
        int q  = 2*j + 1;
        int n1 = q - 127, tt = 2*o - q, d = q - 2*m;
        double ang = chc*(double)(n1*n1) + c*(double)(tt*tt);
        double r = ang*inv2pi; r -= floor(r);
        float af = (float)(r*2.0*PI_D);
        float s = (((d-1)>>1) & 1) ? -2.0f : 2.0f;
        s /= (3.14159265358979f*(float)d);
        float sn, cs; __sincosf(af, &sn, &cs);
        sr += s*cs; si += s*sn;
    }
    int n2 = 2*o - 127;
    double ph = chc*(double)(n2*n2) - PI_D/8.0;
    double r = ph*inv2pi; r -= floor(r);
    float pf = (float)(r*2.0*PI_D);
    float scale = (float)sqrt(c/PI_D);
    float sn, cs; __sincosf(pf, &sn, &cs);
    float cr = cs*scale, ci = sn*scale;
    float2 v = make_float2(sr*cr - si*ci, sr*ci + si*cr);
    g_Mf[tid] = v;
    g_MfT[(m<<7) + o] = v;
    int p = (o*m) & 127;
    float ang2 = TWO_PI_F*(float)p/128.0f;
    float sn2, cs2; __sincosf(ang2, &sn2, &cs2);
    g_F[tid]  = make_float2(cs2, -sn2);
    g_IF[tid] = make_float2(cs2*0.0078125f, sn2*0.0078125f);
}

// ---------------- stream loaders (rmul T-side) -------------------------------
// LM 1: real from x1 slice  2: mag/pha full plane  3: mag/pha packed65 + Hermitian
template<int LM>
__device__ inline void load_T4(float2* tr, const float* mp, const float* pp,
                               const float* Trl, int hh, int w4) {
    if (LM == 1) {
        float4 v = *(const float4*)(Trl + (hh<<7) + w4);
        tr[0] = make_float2(v.x, 0.f); tr[1] = make_float2(v.y, 0.f);
        tr[2] = make_float2(v.z, 0.f); tr[3] = make_float2(v.w, 0.f);
    } else if (LM == 2) {
#pragma unroll
        for (int i = 0; i < 4; ++i) {
            int idx = (hh<<7) + w4 + i;
            float m = mp[idx], ph = pp[idx];
            float sn, cs; __sincosf(ph, &sn, &cs);
            tr[i] = make_float2(m*cs, m*sn);
        }
    } else {
#pragma unroll
        for (int i = 0; i < 4; ++i) {
            int w = w4 + i;
            int h2 = hh, w2 = w; float sg = 1.f;
            if (w >= 65) { h2 = (128 - hh) & 127; w2 = 128 - w; sg = -1.f; }
            int idx = h2*65 + w2;
            float m = mp[idx], ph = pp[idx];
            float sn, cs; __sincosf(ph, &sn, &cs);
            tr[i] = make_float2(m*cs, sg*m*sn);
        }
    }
}

// ---------------- rmul body: out[p,h,j] = sum_w T[p,h,w] * A[j,w] ------------
template<int LM>
__device__ inline void rmul_body(const float2* __restrict__ MT, const float* __restrict__ Trl,
                                 const float* __restrict__ mp_, const float* __restrict__ pp_,
                                 float2* __restrict__ out, int cstart,
                                 int p, int r0, int t, float2* Ssh, float2* Mch) {
    constexpr bool RS = (LM == 1);
    const float* Trp = nullptr; const float* mp = nullptr; const float* pp = nullptr;
    if (LM == 1) { int n = p >> 4, c = p & 15; Trp = Trl + ((long)(n*48 + cstart + c) << 14); }
    if (LM == 2) { mp = mp_ + ((long)p << 14); pp = pp_ + ((long)p << 14); }
    if (LM == 3) { mp = mp_ + (long)p*8320;   pp = pp_ + (long)p*8320; }
    for (int u = t; u < 512; u += 256) {
        int row = u >> 5, w4 = (u & 31) << 2;
        float2 tr4[4];
        load_T4<LM>(tr4, mp, pp, Trp, r0 + row, w4);
        float4* d = (float4*)&Ssh[(row << 7) + w4];
        d[0] = make_float4(tr4[0].x, tr4[0].y, tr4[1].x, tr4[1].y);
        d[1] = make_float4(tr4[2].x, tr4[2].y, tr4[3].x, tr4[3].y);
    }
    float2 acc[4][2] = {};
    int cq = t & 63, rp = t >> 6;
    for (int kc = 0; kc < 128; kc += 32) {
        __syncthreads();
        {
            const float4* Mg = (const float4*)(MT + (kc << 7));
            float4* Md = (float4*)Mch;
            for (int i = t; i < 2048; i += 256) Md[i] = Mg[i];
        }
        __syncthreads();
#pragma unroll
        for (int kk = 0; kk < 32; ++kk) {
            int k = kc + kk;
            float2 s[4], m[2];
#pragma unroll
            for (int i = 0; i < 4; ++i) s[i] = Ssh[(((rp<<2)+i) << 7) + k];
            m[0] = Mch[(kk << 7) + cq];
            m[1] = Mch[(kk << 7) + cq + 64];
#pragma unroll
            for (int i = 0; i < 4; ++i)
#pragma unroll
                for (int q = 0; q < 2; ++q) {
                    if (RS) {
                        acc[i][q].x = fmaf(s[i].x, m[q].x, acc[i][q].x);
                        acc[i][q].y = fmaf(s[i].x, m[q].y, acc[i][q].y);
                    } else {
                        acc[i][q].x = fmaf(s[i].x, m[q].x, acc[i][q].x);
                        acc[i][q].x = fmaf(-s[i].y, m[q].y, acc[i][q].x);
                        acc[i][q].y = fmaf(s[i].x, m[q].y, acc[i][q].y);
                        acc[i][q].y = fmaf(s[i].y, m[q].x, acc[i][q].y);
                    }
                }
        }
    }
    long base = ((long)p << 14);
#pragma unroll
    for (int i = 0; i < 4; ++i) {
        out[base + ((long)(r0 + (rp<<2) + i) << 7) + cq]      = acc[i][0];
        out[base + ((long)(r0 + (rp<<2) + i) << 7) + cq + 64] = acc[i][1];
    }
}

// ---------------- lmul body: out[p,j,w] = sum_h A[j,h] * T[p,h,w] ------------
// EPI 1: mag/pha full  2: abs->cat+coff  3: real-only->cat+coff  4: packed65
template<int EPI>
__device__ inline void lmul_body(const float2* __restrict__ A, const float2* __restrict__ in,
                                 float* __restrict__ o1, float* __restrict__ o2, int coff,
                                 int p, int j0, int t, float2* Ssh, float2* Tch) {
    const float2* T = in + ((long)p << 14);
    {
        const float4* Ag = (const float4*)(A + ((long)j0 << 7));
        float4* Sd = (float4*)Ssh;
        for (int i = t; i < 1024; i += 256) Sd[i] = Ag[i];
    }
    float2 acc[4][2] = {};
    int cq = t & 63, rp = t >> 6;
    for (int kc = 0; kc < 128; kc += 32) {
        __syncthreads();
        {
            const float4* Tg = (const float4*)(T + (kc << 7));
            float4* Td = (float4*)Tch;
            for (int i = t; i < 2048; i += 256) Td[i] = Tg[i];
        }
        __syncthreads();
#pragma unroll
        for (int kk = 0; kk < 32; ++kk) {
            int k = kc + kk;
            float2 s[4], m[2];
#pragma unroll
            for (int i = 0; i < 4; ++i) s[i] = Ssh[(((rp<<2)+i) << 7) + k];
            m[0] = Tch[(kk << 7) + cq];
            m[1] = Tch[(kk << 7) + cq + 64];
#pragma unroll
            for (int i = 0; i < 4; ++i)
#pragma unroll
                for (int q = 0; q < 2; ++q) {
                    if (EPI == 3) {
                        acc[i][q].x = fmaf(s[i].x, m[q].x, acc[i][q].x);
                        acc[i][q].x = fmaf(-s[i].y, m[q].y, acc[i][q].x);
                    } else {
                        acc[i][q].x = fmaf(s[i].x, m[q].x, acc[i][q].x);
                        acc[i][q].x = fmaf(-s[i].y, m[q].y, acc[i][q].x);
                        acc[i][q].y = fmaf(s[i].x, m[q].y, acc[i][q].y);
                        acc[i][q].y = fmaf(s[i].y, m[q].x, acc[i][q].y);
                    }
                }
        }
    }
#pragma unroll
    for (int i = 0; i < 4; ++i) {
#pragma unroll
        for (int q = 0; q < 2; ++q) {
            int jj = j0 + (rp<<2) + i;
            int ww = cq + (q<<6);
            float2 v = acc[i][q];
            if (EPI == 1) {
                long idx = ((long)p << 14) + ((long)jj << 7) + ww;
                o1[idx] = sqrtf(v.x*v.x + v.y*v.y);
                o2[idx] = atan2f(v.y, v.x);
            } else if (EPI == 2) {
                int n = p >> 4, c = p & 15;
                o1[((long)(n*48 + coff + c) << 14) + ((long)jj << 7) + ww] = sqrtf(v.x*v.x + v.y*v.y);
            } else if (EPI == 3) {
                int n = p >> 4, c = p & 15;
                o1[((long)(n*48 + coff + c) << 14) + ((long)jj << 7) + ww] = v.x;
            } else if (EPI == 4) {
                if (ww < 65) {
                    long idx = (long)p*8320 + jj*65 + ww;
                    o1[idx] = sqrtf(v.x*v.x + v.y*v.y);
                    o2[idx] = atan2f(v.y, v.x);
                }
            }
        }
    }
}

// ---------------- dual rmul kernel (+ optional Mb build at bx==8) ------------
template<int LMA, int LMB>
__global__ __launch_bounds__(256, 2)
void k_rmul_dual(const float2* __restrict__ MTa, const float* __restrict__ TrlA,
                 const float* __restrict__ mpA, const float* __restrict__ ppA,
                 float2* __restrict__ outA, int cstartA,
                 const float2* __restrict__ MTb, const float* __restrict__ TrlB,
                 const float* __restrict__ mpB, const float* __restrict__ ppB,
                 float2* __restrict__ outB, int cstartB) {
    __shared__ float2 Ssh[16*128];
    __shared__ float2 Mch[32*128];
    __shared__ float2 W[128];
    int bx = blockIdx.x, by = blockIdx.y, t = threadIdx.x;
    if (bx >= 8) {
        // build Mb + MbT (only dispatched when gridDim.x == 9)
        if (by < 64) {
            if (t < 128) {
                float ang = TWO_PI_F*(float)t/128.0f;
                float sn, cs; __sincosf(ang, &sn, &cs);
                float invs = 0.08838834764831845f;
                W[t] = make_float2(cs*invs, sn*invs);
            }
            __syncthreads();
            int tid = by*256 + t;
            int o = tid >> 7, m = tid & 127;
            float sr = 0.f, si = 0.f;
            for (int r = 0; r < 128; ++r) {
                float2 a = g_Mf[(o<<7) + r];
                int k = ((r+64)*(m+64)) & 127;
                float2 w = W[k];
                sr += a.x*w.x - a.y*w.y;
                si += a.x*w.y + a.y*w.x;
            }
            float2 v = make_float2(sr, si);
            g_Mb[tid] = v;
            g_MbT[(m<<7) + o] = v;
        }
        return;
    }
    int p = by & 63, r0 = bx << 4;
    if (by < 64) rmul_body<LMA>(MTa, TrlA, mpA, ppA, outA, cstartA, p, r0, t, Ssh, Mch);
    else         rmul_body<LMB>(MTb, TrlB, mpB, ppB, outB, cstartB, p, r0, t, Ssh, Mch);
}

// ---------------- dual lmul kernel -------------------------------------------
template<int EPIA, int EPIB>
__global__ __launch_bounds__(256, 2)
void k_lmul_dual(const float2* __restrict__ Aa, const float2* __restrict__ inA,
                 float* __restrict__ o1A, float* __restrict__ o2A, int coffA,
                 const float2* __restrict__ Ab, const float2* __restrict__ inB,
                 float* __restrict__ o1B, float* __restrict__ o2B, int coffB) {
    __shared__ float2 Ssh[16*128];
    __shared__ float2 Tch[32*128];
    int p = blockIdx.y & 63, j0 = blockIdx.x << 4, t = threadIdx.x;
    if (blockIdx.y < 64) lmul_body<EPIA>(Aa, inA, o1A, o2A, coffA, p, j0, t, Ssh, Tch);
    else                 lmul_body<EPIB>(Ab, inB, o1B, o2B, coffB, p, j0, t, Ssh, Tch);
}

// ---------------- wave-level 1x1 conv body -----------------------------------
template<int CIN, int COUT, int KSPLIT, int OSPLIT>
__device__ inline void wconv_body(const float* __restrict__ in, const float* __restrict__ wgt,
                                  const float* __restrict__ bias, float* __restrict__ out,
                                  int S, int Ctin, int cstart, int Ctout, int costart,
                                  int n, int sblk, float* red) {
    constexpr int OW = COUT / OSPLIT;
    constexpr int KC = CIN / KSPLIT;
    int t = threadIdx.x, lane = t & 63;
    int wv = __builtin_amdgcn_readfirstlane(t >> 6);
    int oq = wv / KSPLIT, kq = wv % KSPLIT;
    int s0 = sblk << 7;
    const float* inb = in + ((long)(n*Ctin + cstart + kq*KC))*S + s0 + (lane<<1);
    const float* wb  = wgt + (oq*OW)*CIN + kq*KC;
    float2 acc[OW];
#pragma unroll
    for (int j = 0; j < OW; ++j) acc[j] = make_float2(0.f, 0.f);
#pragma unroll 4
    for (int c = 0; c < KC; ++c) {
        float2 xv = *(const float2*)(inb + (long)c*S);
#pragma unroll
        for (int j = 0; j < OW; ++j) {
            float w = wb[j*CIN + c];
            acc[j].x = fmaf(w, xv.x, acc[j].x);
            acc[j].y = fmaf(w, xv.y, acc[j].y);
        }
    }
    if (KSPLIT == 1) {
#pragma unroll
        for (int j = 0; j < OW; ++j) {
            int o = oq*OW + j;
            float b = bias ? bias[o] : 0.f;
            *(float2*)(out + ((long)(n*Ctout + costart + o))*S + s0 + (lane<<1))
                = make_float2(acc[j].x + b, acc[j].y + b);
        }
    } else {
#pragma unroll
        for (int j = 0; j < OW; ++j) {
            int o = oq*OW + j;
            *(float2*)&red[((kq*COUT + o) << 7) + (lane<<1)] = acc[j];
        }
        __syncthreads();
        for (int idx = t; idx < COUT*64; idx += 256) {
            int o = idx >> 6, l2 = (idx & 63) << 1;
            float b = bias ? bias[o] : 0.f;
            float2 v = make_float2(b, b);
#pragma unroll
            for (int k2 = 0; k2 < KSPLIT; ++k2) {
                float2 r = *(const float2*)&red[((k2*COUT + o) << 7) + l2];
                v.x += r.x; v.y += r.y;
            }
            *(float2*)(out + ((long)(n*Ctout + costart + o))*S + s0 + l2) = v;
        }
    }
}

// ---------------- stage 1: conv1 + matrix builder ----------------------------
__global__ __launch_bounds__(256, 1)
void k_conv1_build(const float* __restrict__ x, const float* __restrict__ w,
                   float* __restrict__ x1) {
    __shared__ float red[2*48*128];
    if (blockIdx.z == 0) {
        wconv_body<192,48,2,2>(x, w, nullptr, x1, 16384, 192, 0, 48, 0,
                               blockIdx.y, blockIdx.x, red);
    } else {
        int b = blockIdx.y*gridDim.x + blockIdx.x;
        if (b < 64) build_A_body(b*256 + threadIdx.x);
    }
}

// ---------------- stage 7: conv2 ---------------------------------------------
__global__ __launch_bounds__(256, 1)
void k_conv2(const float* __restrict__ in, const float* __restrict__ wgt,
             float* __restrict__ out) {
    __shared__ float red[1];
    wconv_body<48,192,1,4>(in, wgt, nullptr, out, 16384, 48, 0, 192, 0,
                           blockIdx.y, blockIdx.x, red);
}

// ---------------- pointwise stage: maskconv + 4 channel-mixes ----------------
__device__ inline void mix16b(const float* __restrict__ in, const float* __restrict__ w,
                              const float* __restrict__ b, float* __restrict__ out,
                              int Ctin, int S, int n, int s0) {
    int t = threadIdx.x, lane = t & 63;
    int oq = __builtin_amdgcn_readfirstlane(t >> 6);
    const float* inb = in + ((long)(n*Ctin))*S + s0 + (lane<<1);
    float2 xv[16];
#pragma unroll
    for (int c = 0; c < 16; ++c) xv[c] = *(const float2*)(inb + (long)c*S);
#pragma unroll
    for (int j = 0; j < 4; ++j) {
        int o = oq*4 + j;
        float bb = b ? b[o] : 0.f;
        float2 a = make_float2(bb, bb);
#pragma unroll
        for (int c = 0; c < 16; ++c) {
            float ww = w[o*16 + c];
            a.x = fmaf(ww, xv[c].x, a.x);
            a.y = fmaf(ww, xv[c].y, a.y);
        }
        *(float2*)(out + ((long)(n*Ctin + o))*S + s0 + (lane<<1)) = a;
    }
}

__device__ inline void maskconv_body(const float* __restrict__ mag, const float* __restrict__ ws3,
                                     const float* __restrict__ bs, const float* __restrict__ wf,
                                     const float* __restrict__ bf, const float* __restrict__ wm,
                                     const float* __restrict__ bm, float* __restrict__ out,
                                     int n, int tile, float (*patch)[324]) {
    int h0 = (tile >> 3) << 4, w0 = (tile & 7) << 4;
    int t = threadIdx.x;
    const float* magn = mag + ((long)n << 18);
    for (int idx = t; idx < 16*324; idx += 256) {
        int c = idx / 324, r = idx - c*324;
        int ph = r / 18, pw = r - ph*18;
        int gh = h0 - 1 + ph, gw = w0 - 1 + pw;
        float v = 0.f;
        if (gh >= 19 && gh < 109 && gw >= 19 && gw < 109)
            v = magn[(c<<14) + (gh<<7) + gw];
        patch[c][r] = v;
    }
    __syncthreads();
    int ty = t >> 4, tx = t & 15;
    int h = h0 + ty, w = w0 + tx;
    bool in1 = (h >= 19 && h < 109 && w >= 19 && w < 109);
    unsigned long long bal = __ballot(in1);
    float res[16];
    if (bal != 0ull) {
        float acc[16];
#pragma unroll
        for (int o = 0; o < 16; ++o) acc[o] = bs[o];
        for (int c = 0; c < 16; ++c) {
            float tap[9];
#pragma unroll
            for (int dh = 0; dh < 3; ++dh)
#pragma unroll
                for (int dw = 0; dw < 3; ++dw)
                    tap[dh*3+dw] = patch[c][(ty+dh)*18 + tx+dw];
            const float* wp = ws3 + c*9;
#pragma unroll
            for (int o = 0; o < 16; ++o)
#pragma unroll
                for (int k = 0; k < 9; ++k)
                    acc[o] = fmaf(wp[o*144 + k], tap[k], acc[o]);
        }
#pragma unroll
        for (int o = 0; o < 16; ++o) res[o] = acc[o];
    }
    if (bal != ~0ull) {
        float xv[16];
#pragma unroll
        for (int c = 0; c < 16; ++c) xv[c] = magn[(c<<14) + (h<<7) + w];
#pragma unroll
        for (int o = 0; o < 16; ++o) {
            float a = bf[o];
#pragma unroll
            for (int c = 0; c < 16; ++c) a = fmaf(wf[o*16 + c], xv[c], a);
            if (!in1) res[o] = a;
        }
    }
#pragma unroll
    for (int o2 = 0; o2 < 16; ++o2) {
        float a = bm[o2];
#pragma unroll
        for (int o = 0; o < 16; ++o)
            a = fmaf(wm[o2*16 + o], res[o], a);
        out[((long)((n<<4) + o2) << 14) + (h << 7) + w] = a;
    }
}

__global__ __launch_bounds__(256, 2)
void k_point(const float* __restrict__ mag, const float* __restrict__ ws3,
             const float* __restrict__ bs, const float* __restrict__ wf,
             const float* __restrict__ bf, const float* __restrict__ wm,
             const float* __restrict__ bm, float* __restrict__ t2,
             const float* __restrict__ pha, const float* __restrict__ pw,
             const float* __restrict__ pb, float* __restrict__ t1,
             const float* __restrict__ x1, const float* __restrict__ c0w,
             const float* __restrict__ c0b, float* __restrict__ cat,
             const float* __restrict__ m65, const float* __restrict__ p65,
             const float* __restrict__ c1w, const float* __restrict__ c1b,
             float* __restrict__ t3, float* __restrict__ t4) {
    __shared__ float patch[16][324];
    int b = blockIdx.x;
    if (b < 256) {
        maskconv_body(mag, ws3, bs, wf, bf, wm, bm, t2, b >> 6, b & 63, patch);
    } else if (b < 768) {
        int i = b - 256;               // pha channel-mix (S=16384, in-place layout 16ch)
        mix16b(pha, pw, pb, t1, 16, 16384, i >> 7, (i & 127) << 7);
    } else if (b < 1280) {
        int i = b - 768;               // conv_0: x1 ch0..15 -> cat ch0..15 (Ct=48)
        mix16b(x1, c0w, c0b, cat, 48, 16384, i >> 7, (i & 127) << 7);
    } else if (b < 1540) {
        int i = b - 1280;              // m65 mix (S=8320)
        mix16b(m65, c1w, c1b, t3, 16, 8320, i / 65, (i % 65) << 7);
    } else {
        int i = b - 1540;              // p65 mix
        mix16b(p65, c1w, c1b, t4, 16, 8320, i / 65, (i % 65) << 7);
    }
}

// ---------------- launch ----------------------------------------------------
extern "C" void kernel_launch(void* const* d_in, const int* in_sizes, int n_in,
                              void* d_out, int out_size, void* d_ws, size_t ws_size,
                              hipStream_t stream) {
    (void)in_sizes; (void)n_in; (void)out_size; (void)d_ws; (void)ws_size;
    const float* x        = (const float*)d_in[0];
    const float* conv1_w  = (const float*)d_in[1];
    const float* mag_s_w  = (const float*)d_in[2];
    const float* mag_s_b  = (const float*)d_in[3];
    const float* mag_f_w  = (const float*)d_in[4];
    const float* mag_f_b  = (const float*)d_in[5];
    const float* mag_w_   = (const float*)d_in[6];
    const float* mag_b_   = (const float*)d_in[7];
    const float* pha_w_   = (const float*)d_in[8];
    const float* pha_b_   = (const float*)d_in[9];
    const float* conv_0_w = (const float*)d_in[10];
    const float* conv_0_b = (const float*)d_in[11];
    const float* conv_1_w = (const float*)d_in[12];
    const float* conv_1_b = (const float*)d_in[13];
    const float* conv2_w  = (const float*)d_in[14];
    float* outp = (float*)d_out;

    float2 *Mf, *MfT, *Mb, *MbT, *Fm, *IFm, *bufA, *bufB;
    float *x1, *mag, *pha, *m65, *p65, *t1, *t2, *t3, *t4, *cat;
    hipGetSymbolAddress((void**)&Mf,   HIP_SYMBOL(g_Mf));
    hipGetSymbolAddress((void**)&MfT,  HIP_SYMBOL(g_MfT));
    hipGetSymbolAddress((void**)&Mb,   HIP_SYMBOL(g_Mb));
    hipGetSymbolAddress((void**)&MbT,  HIP_SYMBOL(g_MbT));
    hipGetSymbolAddress((void**)&Fm,   HIP_SYMBOL(g_F));
    hipGetSymbolAddress((void**)&IFm,  HIP_SYMBOL(g_IF));
    hipGetSymbolAddress((void**)&bufA, HIP_SYMBOL(g_bufA));
    hipGetSymbolAddress((void**)&bufB, HIP_SYMBOL(g_bufB));
    hipGetSymbolAddress((void**)&x1,   HIP_SYMBOL(g_x1));
    hipGetSymbolAddress((void**)&mag,  HIP_SYMBOL(g_mag));
    hipGetSymbolAddress((void**)&pha,  HIP_SYMBOL(g_pha));
    hipGetSymbolAddress((void**)&m65,  HIP_SYMBOL(g_m65));
    hipGetSymbolAddress((void**)&p65,  HIP_SYMBOL(g_p65));
    hipGetSymbolAddress((void**)&t1,   HIP_SYMBOL(g_t1));
    hipGetSymbolAddress((void**)&t2,   HIP_SYMBOL(g_t2));
    hipGetSymbolAddress((void**)&t3,   HIP_SYMBOL(g_t3));
    hipGetSymbolAddress((void**)&t4,   HIP_SYMBOL(g_t4));
    hipGetSymbolAddress((void**)&cat,  HIP_SYMBOL(g_cat));

    dim3 bt(256, 1, 1);

    // stage 1: conv1 (x -> x1) + build Mf/MfT/F/IF
    k_conv1_build<<<dim3(128,4,2), bt, 0, stream>>>(x, conv1_w, x1);

    // stage 2: dual rmul (FRFT fwd ch16..31 -> bufA; FFT fwd ch32..47 -> bufB) + build Mb
    k_rmul_dual<1,1><<<dim3(9,128), bt, 0, stream>>>(
        MfT, x1, nullptr, nullptr, bufA, 16,
        Fm,  x1, nullptr, nullptr, bufB, 32);

    // stage 3: dual lmul (mag/pha full <- bufA; packed65 <- bufB)
    k_lmul_dual<1,4><<<dim3(8,128), bt, 0, stream>>>(
        Mf, bufA, mag, pha, 0,
        Fm, bufB, m65, p65, 0);

    // stage 4: maskconv(+mag mix) -> t2 | pha mix -> t1 | conv_0 -> cat0 |
    //          m65 mix -> t3 | p65 mix -> t4
    k_point<<<1800, bt, 0, stream>>>(mag, mag_s_w, mag_s_b, mag_f_w, mag_f_b,
                                     mag_w_, mag_b_, t2,
                                     pha, pha_w_, pha_b_, t1,
                                     x1, conv_0_w, conv_0_b, cat,
                                     m65, p65, conv_1_w, conv_1_b, t3, t4);

    // stage 5: dual rmul (FRFT bwd combine(t2,t1) -> bufA; irfft combine65(t3,t4) -> bufB)
    k_rmul_dual<2,3><<<dim3(8,128), bt, 0, stream>>>(
        MbT, nullptr, t2, t1, bufA, 0,
        IFm, nullptr, t3, t4, bufB, 0);

    // stage 6: dual lmul (abs -> cat ch16..31; real -> cat ch32..47)
    k_lmul_dual<2,3><<<dim3(8,128), bt, 0, stream>>>(
        Mb,  bufA, cat, nullptr, 16,
        IFm, bufB, cat, nullptr, 32);

    // stage 7: conv2 (cat -> out)
    k_conv2<<<dim3(128,4), bt, 0, stream>>>(cat, conv2_w, outp);
}

// Round 10
// 337.942 us; speedup vs baseline: 1.6652x; 1.0474x over previous
//
#include <hip/hip_runtime.h>
#include <math.h>

#define PI_D 3.14159265358979323846
#define TWO_PI_F 6.2831853071795864f

// ---------------- persistent device buffers ---------------------------------
__device__ __align__(16) float2 g_Mf [128*128];
__device__ __align__(16) float2 g_MfT[128*128];
__device__ __align__(16) float2 g_Mb [128*128];
__device__ __align__(16) float2 g_MbT[128*128];
__device__ __align__(16) float2 g_F  [128*128];   // symmetric
__device__ __align__(16) float2 g_IF [128*128];   // symmetric
__device__ __align__(16) float  g_x1 [4*48*16384];
__device__ __align__(16) float2 g_bufA[64*16384];
__device__ __align__(16) float2 g_bufB[64*16384];
__device__ __align__(16) float  g_mag[64*16384];
__device__ __align__(16) float  g_pha[64*16384];
__device__ __align__(16) float  g_m65[64*8320];
__device__ __align__(16) float  g_p65[64*8320];
__device__ __align__(16) float  g_t1 [64*16384];
__device__ __align__(16) float  g_t2 [64*16384];
__device__ __align__(16) float  g_t3 [64*8320];
__device__ __align__(16) float  g_t4 [64*8320];
__device__ __align__(16) float  g_cat[4*48*16384];

// ---------------- builder bodies ---------------------------------------------
__device__ inline void build_A_body(int tid) {
    if (tid >= 128*128) return;
    int o = tid >> 7, m = tid & 127;
    const double chc = -PI_D/128.0 * tan(PI_D/8.0) * 0.25;
    const double c   =  PI_D/(512.0*sin(PI_D/4.0));
    const double inv2pi = 1.0/(2.0*PI_D);
    float sr, si;
    {   // q = 2m term (sinc = 1)
        int n1 = 2*m - 127, tt = 2*(o - m);
        double ang = chc*(double)(n1*n1) + c*(double)(tt*tt);
        double r = ang*inv2pi; r -= floor(r);
        float af = (float)(r*2.0*PI_D);
        float sn, cs; __sincosf(af, &sn, &cs);
        sr = cs; si = sn;
    }
    for (int j = 0; j < 127; ++j) {
        int q  = 2*j + 1;
        int n1 = q - 127, tt = 2*o - q, d = q - 2*m;
        double ang = chc*(double)(n1*n1) + c*(double)(tt*tt);
        double r = ang*inv2pi; r -= floor(r);
        float af = (float)(r*2.0*PI_D);
        float s = (((d-1)>>1) & 1) ? -2.0f : 2.0f;
        s /= (3.14159265358979f*(float)d);
        float sn, cs; __sincosf(af, &sn, &cs);
        sr += s*cs; si += s*sn;
    }
    int n2 = 2*o - 127;
    double ph = chc*(double)(n2*n2) - PI_D/8.0;
    double r = ph*inv2pi; r -= floor(r);
    float pf = (float)(r*2.0*PI_D);
    float scale = (float)sqrt(c/PI_D);
    float sn, cs; __sincosf(pf, &sn, &cs);
    float cr = cs*scale, ci = sn*scale;
    float2 v = make_float2(sr*cr - si*ci, sr*ci + si*cr);
    g_Mf[tid] = v;
    g_MfT[(m<<7) + o] = v;
    int p = (o*m) & 127;
    float ang2 = TWO_PI_F*(float)p/128.0f;
    float sn2, cs2; __sincosf(ang2, &sn2, &cs2);
    g_F[tid]  = make_float2(cs2, -sn2);
    g_IF[tid] = make_float2(cs2*0.0078125f, sn2*0.0078125f);
}

// ---------------- stream loaders (rmul T-side) -------------------------------
// LM 1: real from x1 slice  2: mag/pha full plane  3: mag/pha packed65 + Hermitian
template<int LM>
__device__ inline void load_T4(float2* tr, const float* mp, const float* pp,
                               const float* Trl, int hh, int w4) {
    if (LM == 1) {
        float4 v = *(const float4*)(Trl + (hh<<7) + w4);
        tr[0] = make_float2(v.x, 0.f); tr[1] = make_float2(v.y, 0.f);
        tr[2] = make_float2(v.z, 0.f); tr[3] = make_float2(v.w, 0.f);
    } else if (LM == 2) {
#pragma unroll
        for (int i = 0; i < 4; ++i) {
            int idx = (hh<<7) + w4 + i;
            float m = mp[idx], ph = pp[idx];
            float sn, cs; __sincosf(ph, &sn, &cs);
            tr[i] = make_float2(m*cs, m*sn);
        }
    } else {
#pragma unroll
        for (int i = 0; i < 4; ++i) {
            int w = w4 + i;
            int h2 = hh, w2 = w; float sg = 1.f;
            if (w >= 65) { h2 = (128 - hh) & 127; w2 = 128 - w; sg = -1.f; }
            int idx = h2*65 + w2;
            float m = mp[idx], ph = pp[idx];
            float sn, cs; __sincosf(ph, &sn, &cs);
            tr[i] = make_float2(m*cs, sg*m*sn);
        }
    }
}

// ---------------- rmul body: out[p,h,j] = sum_w T[p,h,w] * A[j,w] ------------
template<int LM>
__device__ inline void rmul_body(const float2* __restrict__ MT, const float* __restrict__ Trl,
                                 const float* __restrict__ mp_, const float* __restrict__ pp_,
                                 float2* __restrict__ out, int cstart,
                                 int p, int r0, int t, float2* Ssh, float2* Mch) {
    constexpr bool RS = (LM == 1);
    const float* Trp = nullptr; const float* mp = nullptr; const float* pp = nullptr;
    if (LM == 1) { int n = p >> 4, c = p & 15; Trp = Trl + ((long)(n*48 + cstart + c) << 14); }
    if (LM == 2) { mp = mp_ + ((long)p << 14); pp = pp_ + ((long)p << 14); }
    if (LM == 3) { mp = mp_ + (long)p*8320;   pp = pp_ + (long)p*8320; }
    for (int u = t; u < 512; u += 256) {
        int row = u >> 5, w4 = (u & 31) << 2;
        float2 tr4[4];
        load_T4<LM>(tr4, mp, pp, Trp, r0 + row, w4);
        float4* d = (float4*)&Ssh[(row << 7) + w4];
        d[0] = make_float4(tr4[0].x, tr4[0].y, tr4[1].x, tr4[1].y);
        d[1] = make_float4(tr4[2].x, tr4[2].y, tr4[3].x, tr4[3].y);
    }
    float2 acc[4][2] = {};
    int cq = t & 63, rp = t >> 6;
    for (int kc = 0; kc < 128; kc += 32) {
        __syncthreads();
        {
            const float4* Mg = (const float4*)(MT + (kc << 7));
            float4* Md = (float4*)Mch;
            for (int i = t; i < 2048; i += 256) Md[i] = Mg[i];
        }
        __syncthreads();
#pragma unroll
        for (int kk = 0; kk < 32; ++kk) {
            int k = kc + kk;
            float2 s[4], m[2];
#pragma unroll
            for (int i = 0; i < 4; ++i) s[i] = Ssh[(((rp<<2)+i) << 7) + k];
            m[0] = Mch[(kk << 7) + cq];
            m[1] = Mch[(kk << 7) + cq + 64];
#pragma unroll
            for (int i = 0; i < 4; ++i)
#pragma unroll
                for (int q = 0; q < 2; ++q) {
                    if (RS) {
                        acc[i][q].x = fmaf(s[i].x, m[q].x, acc[i][q].x);
                        acc[i][q].y = fmaf(s[i].x, m[q].y, acc[i][q].y);
                    } else {
                        acc[i][q].x = fmaf(s[i].x, m[q].x, acc[i][q].x);
                        acc[i][q].x = fmaf(-s[i].y, m[q].y, acc[i][q].x);
                        acc[i][q].y = fmaf(s[i].x, m[q].y, acc[i][q].y);
                        acc[i][q].y = fmaf(s[i].y, m[q].x, acc[i][q].y);
                    }
                }
        }
    }
    long base = ((long)p << 14);
#pragma unroll
    for (int i = 0; i < 4; ++i) {
        out[base + ((long)(r0 + (rp<<2) + i) << 7) + cq]      = acc[i][0];
        out[base + ((long)(r0 + (rp<<2) + i) << 7) + cq + 64] = acc[i][1];
    }
}

// ---------------- lmul body: out[p,j,w] = sum_h A[j,h] * T[p,h,w] ------------
// T chunked by 16 rows (32 KB total LDS). EPI 1: mag/pha full  2: abs->cat+coff
// 3: real-only->cat+coff  4: packed65
template<int EPI>
__device__ inline void lmul_body(const float2* __restrict__ A, const float2* __restrict__ in,
                                 float* __restrict__ o1, float* __restrict__ o2, int coff,
                                 int p, int j0, int t, float2* Ssh, float2* Tch) {
    const float2* T = in + ((long)p << 14);
    {
        const float4* Ag = (const float4*)(A + ((long)j0 << 7));
        float4* Sd = (float4*)Ssh;
        for (int i = t; i < 1024; i += 256) Sd[i] = Ag[i];
    }
    float2 acc[4][2] = {};
    int cq = t & 63, rp = t >> 6;
    for (int kc = 0; kc < 128; kc += 16) {
        __syncthreads();
        {
            const float4* Tg = (const float4*)(T + (kc << 7));
            float4* Td = (float4*)Tch;
            for (int i = t; i < 1024; i += 256) Td[i] = Tg[i];
        }
        __syncthreads();
#pragma unroll
        for (int kk = 0; kk < 16; ++kk) {
            int k = kc + kk;
            float2 s[4], m[2];
#pragma unroll
            for (int i = 0; i < 4; ++i) s[i] = Ssh[(((rp<<2)+i) << 7) + k];
            m[0] = Tch[(kk << 7) + cq];
            m[1] = Tch[(kk << 7) + cq + 64];
#pragma unroll
            for (int i = 0; i < 4; ++i)
#pragma unroll
                for (int q = 0; q < 2; ++q) {
                    if (EPI == 3) {
                        acc[i][q].x = fmaf(s[i].x, m[q].x, acc[i][q].x);
                        acc[i][q].x = fmaf(-s[i].y, m[q].y, acc[i][q].x);
                    } else {
                        acc[i][q].x = fmaf(s[i].x, m[q].x, acc[i][q].x);
                        acc[i][q].x = fmaf(-s[i].y, m[q].y, acc[i][q].x);
                        acc[i][q].y = fmaf(s[i].x, m[q].y, acc[i][q].y);
                        acc[i][q].y = fmaf(s[i].y, m[q].x, acc[i][q].y);
                    }
                }
        }
    }
#pragma unroll
    for (int i = 0; i < 4; ++i) {
#pragma unroll
        for (int q = 0; q < 2; ++q) {
            int jj = j0 + (rp<<2) + i;
            int ww = cq + (q<<6);
            float2 v = acc[i][q];
            if (EPI == 1) {
                long idx = ((long)p << 14) + ((long)jj << 7) + ww;
                o1[idx] = sqrtf(v.x*v.x + v.y*v.y);
                o2[idx] = atan2f(v.y, v.x);
            } else if (EPI == 2) {
                int n = p >> 4, c = p & 15;
                o1[((long)(n*48 + coff + c) << 14) + ((long)jj << 7) + ww] = sqrtf(v.x*v.x + v.y*v.y);
            } else if (EPI == 3) {
                int n = p >> 4, c = p & 15;
                o1[((long)(n*48 + coff + c) << 14) + ((long)jj << 7) + ww] = v.x;
            } else if (EPI == 4) {
                if (ww < 65) {
                    long idx = (long)p*8320 + jj*65 + ww;
                    o1[idx] = sqrtf(v.x*v.x + v.y*v.y);
                    o2[idx] = atan2f(v.y, v.x);
                }
            }
        }
    }
}

// ---------------- dual rmul kernel (+ Mb build at bx>=128) -------------------
// grid (136, 8): bx<128 -> plane bx (A: 0..63, B: 64..127), by = strip.
// Linear id % 8 == bx % 8 -> all strips of a plane land on one XCD.
template<int LMA, int LMB>
__global__ __launch_bounds__(256, 3)
void k_rmul_dual(const float2* __restrict__ MTa, const float* __restrict__ TrlA,
                 const float* __restrict__ mpA, const float* __restrict__ ppA,
                 float2* __restrict__ outA, int cstartA,
                 const float2* __restrict__ MTb, const float* __restrict__ TrlB,
                 const float* __restrict__ mpB, const float* __restrict__ ppB,
                 float2* __restrict__ outB, int cstartB) {
    __shared__ float2 Ssh[16*128];
    __shared__ float2 Mch[32*128];
    __shared__ float2 W[128];
    int bx = blockIdx.x, by = blockIdx.y, t = threadIdx.x;
    if (bx >= 128) {
        // build Mb + MbT: 64 blocks (bx-128)*8+by over 16384 entries
        int b = (bx - 128)*8 + by;
        if (b < 64) {
            if (t < 128) {
                float ang = TWO_PI_F*(float)t/128.0f;
                float sn, cs; __sincosf(ang, &sn, &cs);
                float invs = 0.08838834764831845f;
                W[t] = make_float2(cs*invs, sn*invs);
            }
            __syncthreads();
            int tid = b*256 + t;
            int o = tid >> 7, m = tid & 127;
            float sr = 0.f, si = 0.f;
            for (int r = 0; r < 128; ++r) {
                float2 a = g_Mf[(o<<7) + r];
                int k = ((r+64)*(m+64)) & 127;
                float2 w = W[k];
                sr += a.x*w.x - a.y*w.y;
                si += a.x*w.y + a.y*w.x;
            }
            float2 v = make_float2(sr, si);
            g_Mb[tid] = v;
            g_MbT[(m<<7) + o] = v;
        }
        return;
    }
    int p = bx & 63, r0 = by << 4;
    if (bx < 64) rmul_body<LMA>(MTa, TrlA, mpA, ppA, outA, cstartA, p, r0, t, Ssh, Mch);
    else         rmul_body<LMB>(MTb, TrlB, mpB, ppB, outB, cstartB, p, r0, t, Ssh, Mch);
}

// ---------------- dual lmul kernel (XCD-pinned planes) -----------------------
template<int EPIA, int EPIB>
__global__ __launch_bounds__(256, 4)
void k_lmul_dual(const float2* __restrict__ Aa, const float2* __restrict__ inA,
                 float* __restrict__ o1A, float* __restrict__ o2A, int coffA,
                 const float2* __restrict__ Ab, const float2* __restrict__ inB,
                 float* __restrict__ o1B, float* __restrict__ o2B, int coffB) {
    __shared__ float2 Ssh[16*128];
    __shared__ float2 Tch[16*128];
    int bx = blockIdx.x, j0 = blockIdx.y << 4, t = threadIdx.x;
    int p = bx & 63;
    if (bx < 64) lmul_body<EPIA>(Aa, inA, o1A, o2A, coffA, p, j0, t, Ssh, Tch);
    else         lmul_body<EPIB>(Ab, inB, o1B, o2B, coffB, p, j0, t, Ssh, Tch);
}

// ---------------- wave-level 1x1 conv body -----------------------------------
template<int CIN, int COUT, int KSPLIT, int OSPLIT>
__device__ inline void wconv_body(const float* __restrict__ in, const float* __restrict__ wgt,
                                  const float* __restrict__ bias, float* __restrict__ out,
                                  int S, int Ctin, int cstart, int Ctout, int costart,
                                  int n, int sblk, float* red) {
    constexpr int OW = COUT / OSPLIT;
    constexpr int KC = CIN / KSPLIT;
    int t = threadIdx.x, lane = t & 63;
    int wv = __builtin_amdgcn_readfirstlane(t >> 6);
    int oq = wv / KSPLIT, kq = wv % KSPLIT;
    int s0 = sblk << 7;
    const float* inb = in + ((long)(n*Ctin + cstart + kq*KC))*S + s0 + (lane<<1);
    const float* wb  = wgt + (oq*OW)*CIN + kq*KC;
    float2 acc[OW];
#pragma unroll
    for (int j = 0; j < OW; ++j) acc[j] = make_float2(0.f, 0.f);
#pragma unroll 4
    for (int c = 0; c < KC; ++c) {
        float2 xv = *(const float2*)(inb + (long)c*S);
#pragma unroll
        for (int j = 0; j < OW; ++j) {
            float w = wb[j*CIN + c];
            acc[j].x = fmaf(w, xv.x, acc[j].x);
            acc[j].y = fmaf(w, xv.y, acc[j].y);
        }
    }
    if (KSPLIT == 1) {
#pragma unroll
        for (int j = 0; j < OW; ++j) {
            int o = oq*OW + j;
            float b = bias ? bias[o] : 0.f;
            *(float2*)(out + ((long)(n*Ctout + costart + o))*S + s0 + (lane<<1))
                = make_float2(acc[j].x + b, acc[j].y + b);
        }
    } else {
#pragma unroll
        for (int j = 0; j < OW; ++j) {
            int o = oq*OW + j;
            *(float2*)&red[((kq*COUT + o) << 7) + (lane<<1)] = acc[j];
        }
        __syncthreads();
        for (int idx = t; idx < COUT*64; idx += 256) {
            int o = idx >> 6, l2 = (idx & 63) << 1;
            float b = bias ? bias[o] : 0.f;
            float2 v = make_float2(b, b);
#pragma unroll
            for (int k2 = 0; k2 < KSPLIT; ++k2) {
                float2 r = *(const float2*)&red[((k2*COUT + o) << 7) + l2];
                v.x += r.x; v.y += r.y;
            }
            *(float2*)(out + ((long)(n*Ctout + costart + o))*S + s0 + l2) = v;
        }
    }
}

// ---------------- stage 1: conv1 + matrix builder ----------------------------
__global__ __launch_bounds__(256, 1)
void k_conv1_build(const float* __restrict__ x, const float* __restrict__ w,
                   float* __restrict__ x1) {
    __shared__ float red[2*48*128];
    if (blockIdx.z == 0) {
        wconv_body<192,48,2,2>(x, w, nullptr, x1, 16384, 192, 0, 48, 0,
                               blockIdx.y, blockIdx.x, red);
    } else {
        int b = blockIdx.y*gridDim.x + blockIdx.x;
        if (b < 64) build_A_body(b*256 + threadIdx.x);
    }
}

// ---------------- stage 7: conv2 ---------------------------------------------
__global__ __launch_bounds__(256, 1)
void k_conv2(const float* __restrict__ in, const float* __restrict__ wgt,
             float* __restrict__ out) {
    __shared__ float red[1];
    wconv_body<48,192,1,4>(in, wgt, nullptr, out, 16384, 48, 0, 192, 0,
                           blockIdx.y, blockIdx.x, red);
}

// ---------------- pointwise stage: maskconv + 4 channel-mixes ----------------
__device__ inline void mix16b(const float* __restrict__ in, const float* __restrict__ w,
                              const float* __restrict__ b, float* __restrict__ out,
                              int Ctin, int S, int n, int s0) {
    int t = threadIdx.x, lane = t & 63;
    int oq = __builtin_amdgcn_readfirstlane(t >> 6);
    const float* inb = in + ((long)(n*Ctin))*S + s0 + (lane<<1);
    float2 xv[16];
#pragma unroll
    for (int c = 0; c < 16; ++c) xv[c] = *(const float2*)(inb + (long)c*S);
#pragma unroll
    for (int j = 0; j < 4; ++j) {
        int o = oq*4 + j;
        float bb = b ? b[o] : 0.f;
        float2 a = make_float2(bb, bb);
#pragma unroll
        for (int c = 0; c < 16; ++c) {
            float ww = w[o*16 + c];
            a.x = fmaf(ww, xv[c].x, a.x);
            a.y = fmaf(ww, xv[c].y, a.y);
        }
        *(float2*)(out + ((long)(n*Ctin + o))*S + s0 + (lane<<1)) = a;
    }
}

__device__ inline void maskconv_body(const float* __restrict__ mag, const float* __restrict__ ws3,
                                     const float* __restrict__ bs, const float* __restrict__ wf,
                                     const float* __restrict__ bf, const float* __restrict__ wm,
                                     const float* __restrict__ bm, float* __restrict__ out,
                                     int n, int tile, float (*patch)[324]) {
    int h0 = (tile >> 3) << 4, w0 = (tile & 7) << 4;
    int t = threadIdx.x;
    const float* magn = mag + ((long)n << 18);
    for (int idx = t; idx < 16*324; idx += 256) {
        int c = idx / 324, r = idx - c*324;
        int ph = r / 18, pw = r - ph*18;
        int gh = h0 - 1 + ph, gw = w0 - 1 + pw;
        float v = 0.f;
        if (gh >= 19 && gh < 109 && gw >= 19 && gw < 109)
            v = magn[(c<<14) + (gh<<7) + gw];
        patch[c][r] = v;
    }
    __syncthreads();
    int ty = t >> 4, tx = t & 15;
    int h = h0 + ty, w = w0 + tx;
    bool in1 = (h >= 19 && h < 109 && w >= 19 && w < 109);
    unsigned long long bal = __ballot(in1);
    float res[16];
    if (bal != 0ull) {
        float acc[16];
#pragma unroll
        for (int o = 0; o < 16; ++o) acc[o] = bs[o];
        for (int c = 0; c < 16; ++c) {
            float tap[9];
#pragma unroll
            for (int dh = 0; dh < 3; ++dh)
#pragma unroll
                for (int dw = 0; dw < 3; ++dw)
                    tap[dh*3+dw] = patch[c][(ty+dh)*18 + tx+dw];
            const float* wp = ws3 + c*9;
#pragma unroll
            for (int o = 0; o < 16; ++o)
#pragma unroll
                for (int k = 0; k < 9; ++k)
                    acc[o] = fmaf(wp[o*144 + k], tap[k], acc[o]);
        }
#pragma unroll
        for (int o = 0; o < 16; ++o) res[o] = acc[o];
    }
    if (bal != ~0ull) {
        float xv[16];
#pragma unroll
        for (int c = 0; c < 16; ++c) xv[c] = magn[(c<<14) + (h<<7) + w];
#pragma unroll
        for (int o = 0; o < 16; ++o) {
            float a = bf[o];
#pragma unroll
            for (int c = 0; c < 16; ++c) a = fmaf(wf[o*16 + c], xv[c], a);
            if (!in1) res[o] = a;
        }
    }
#pragma unroll
    for (int o2 = 0; o2 < 16; ++o2) {
        float a = bm[o2];
#pragma unroll
        for (int o = 0; o < 16; ++o)
            a = fmaf(wm[o2*16 + o], res[o], a);
        out[((long)((n<<4) + o2) << 14) + (h << 7) + w] = a;
    }
}

__global__ __launch_bounds__(256, 2)
void k_point(const float* __restrict__ mag, const float* __restrict__ ws3,
             const float* __restrict__ bs, const float* __restrict__ wf,
             const float* __restrict__ bf, const float* __restrict__ wm,
             const float* __restrict__ bm, float* __restrict__ t2,
             const float* __restrict__ pha, const float* __restrict__ pw,
             const float* __restrict__ pb, float* __restrict__ t1,
             const float* __restrict__ x1, const float* __restrict__ c0w,
             const float* __restrict__ c0b, float* __restrict__ cat,
             const float* __restrict__ m65, const float* __restrict__ p65,
             const float* __restrict__ c1w, const float* __restrict__ c1b,
             float* __restrict__ t3, float* __restrict__ t4) {
    __shared__ float patch[16][324];
    int b = blockIdx.x;
    if (b < 256) {
        maskconv_body(mag, ws3, bs, wf, bf, wm, bm, t2, b >> 6, b & 63, patch);
    } else if (b < 768) {
        int i = b - 256;               // pha channel-mix (S=16384)
        mix16b(pha, pw, pb, t1, 16, 16384, i >> 7, (i & 127) << 7);
    } else if (b < 1280) {
        int i = b - 768;               // conv_0: x1 ch0..15 -> cat ch0..15 (Ct=48)
        mix16b(x1, c0w, c0b, cat, 48, 16384, i >> 7, (i & 127) << 7);
    } else if (b < 1540) {
        int i = b - 1280;              // m65 mix (S=8320)
        mix16b(m65, c1w, c1b, t3, 16, 8320, i / 65, (i % 65) << 7);
    } else {
        int i = b - 1540;              // p65 mix
        mix16b(p65, c1w, c1b, t4, 16, 8320, i / 65, (i % 65) << 7);
    }
}

// ---------------- launch ----------------------------------------------------
extern "C" void kernel_launch(void* const* d_in, const int* in_sizes, int n_in,
                              void* d_out, int out_size, void* d_ws, size_t ws_size,
                              hipStream_t stream) {
    (void)in_sizes; (void)n_in; (void)out_size; (void)d_ws; (void)ws_size;
    const float* x        = (const float*)d_in[0];
    const float* conv1_w  = (const float*)d_in[1];
    const float* mag_s_w  = (const float*)d_in[2];
    const float* mag_s_b  = (const float*)d_in[3];
    const float* mag_f_w  = (const float*)d_in[4];
    const float* mag_f_b  = (const float*)d_in[5];
    const float* mag_w_   = (const float*)d_in[6];
    const float* mag_b_   = (const float*)d_in[7];
    const float* pha_w_   = (const float*)d_in[8];
    const float* pha_b_   = (const float*)d_in[9];
    const float* conv_0_w = (const float*)d_in[10];
    const float* conv_0_b = (const float*)d_in[11];
    const float* conv_1_w = (const float*)d_in[12];
    const float* conv_1_b = (const float*)d_in[13];
    const float* conv2_w  = (const float*)d_in[14];
    float* outp = (float*)d_out;

    float2 *Mf, *MfT, *Mb, *MbT, *Fm, *IFm, *bufA, *bufB;
    float *x1, *mag, *pha, *m65, *p65, *t1, *t2, *t3, *t4, *cat;
    hipGetSymbolAddress((void**)&Mf,   HIP_SYMBOL(g_Mf));
    hipGetSymbolAddress((void**)&MfT,  HIP_SYMBOL(g_MfT));
    hipGetSymbolAddress((void**)&Mb,   HIP_SYMBOL(g_Mb));
    hipGetSymbolAddress((void**)&MbT,  HIP_SYMBOL(g_MbT));
    hipGetSymbolAddress((void**)&Fm,   HIP_SYMBOL(g_F));
    hipGetSymbolAddress((void**)&IFm,  HIP_SYMBOL(g_IF));
    hipGetSymbolAddress((void**)&bufA, HIP_SYMBOL(g_bufA));
    hipGetSymbolAddress((void**)&bufB, HIP_SYMBOL(g_bufB));
    hipGetSymbolAddress((void**)&x1,   HIP_SYMBOL(g_x1));
    hipGetSymbolAddress((void**)&mag,  HIP_SYMBOL(g_mag));
    hipGetSymbolAddress((void**)&pha,  HIP_SYMBOL(g_pha));
    hipGetSymbolAddress((void**)&m65,  HIP_SYMBOL(g_m65));
    hipGetSymbolAddress((void**)&p65,  HIP_SYMBOL(g_p65));
    hipGetSymbolAddress((void**)&t1,   HIP_SYMBOL(g_t1));
    hipGetSymbolAddress((void**)&t2,   HIP_SYMBOL(g_t2));
    hipGetSymbolAddress((void**)&t3,   HIP_SYMBOL(g_t3));
    hipGetSymbolAddress((void**)&t4,   HIP_SYMBOL(g_t4));
    hipGetSymbolAddress((void**)&cat,  HIP_SYMBOL(g_cat));

    dim3 bt(256, 1, 1);

    // stage 1: conv1 (x -> x1) + build Mf/MfT/F/IF
    k_conv1_build<<<dim3(128,4,2), bt, 0, stream>>>(x, conv1_w, x1);

    // stage 2: dual rmul (FRFT fwd -> bufA; FFT fwd -> bufB) + build Mb
    k_rmul_dual<1,1><<<dim3(136,8), bt, 0, stream>>>(
        MfT, x1, nullptr, nullptr, bufA, 16,
        Fm,  x1, nullptr, nullptr, bufB, 32);

    // stage 3: dual lmul (mag/pha full <- bufA; packed65 <- bufB)
    k_lmul_dual<1,4><<<dim3(128,8), bt, 0, stream>>>(
        Mf, bufA, mag, pha, 0,
        Fm, bufB, m65, p65, 0);

    // stage 4: maskconv(+mag mix) | pha mix | conv_0 | m65 mix | p65 mix
    k_point<<<1800, bt, 0, stream>>>(mag, mag_s_w, mag_s_b, mag_f_w, mag_f_b,
                                     mag_w_, mag_b_, t2,
                                     pha, pha_w_, pha_b_, t1,
                                     x1, conv_0_w, conv_0_b, cat,
                                     m65, p65, conv_1_w, conv_1_b, t3, t4);

    // stage 5: dual rmul (FRFT bwd combine(t2,t1) -> bufA; irfft combine65(t3,t4) -> bufB)
    k_rmul_dual<2,3><<<dim3(128,8), bt, 0, stream>>>(
        MbT, nullptr, t2, t1, bufA, 0,
        IFm, nullptr, t3, t4, bufB, 0);

    // stage 6: dual lmul (abs -> cat ch16..31; real -> cat ch32..47)
    k_lmul_dual<2,3><<<dim3(128,8), bt, 0, stream>>>(
        Mb,  bufA, cat, nullptr, 16,
        IFm, bufB, cat, nullptr, 32);

    // stage 7: conv2 (cat -> out)
    k_conv2<<<dim3(128,4), bt, 0, stream>>>(cat, conv2_w, outp);
}

// Round 11
// 331.717 us; speedup vs baseline: 1.6965x; 1.0188x over previous
//
#include <hip/hip_runtime.h>
#include <math.h>

#define PI_D 3.14159265358979323846
#define TWO_PI_F 6.2831853071795864f

// ---------------- persistent device buffers ---------------------------------
__device__ __align__(16) float2 g_Mf [128*128];
__device__ __align__(16) float2 g_MfT[128*128];
__device__ __align__(16) float2 g_Mb [128*128];
__device__ __align__(16) float2 g_MbT[128*128];
__device__ __align__(16) float2 g_F  [128*128];   // symmetric
__device__ __align__(16) float2 g_IF [128*128];   // symmetric
__device__ __align__(16) float  g_x1 [4*48*16384];
__device__ __align__(16) float2 g_bufA[64*16384];
__device__ __align__(16) float2 g_bufB[64*16384];
__device__ __align__(16) float  g_mag[64*16384];
__device__ __align__(16) float  g_pha[64*16384];
__device__ __align__(16) float  g_m65[64*8320];
__device__ __align__(16) float  g_p65[64*8320];
__device__ __align__(16) float  g_t1 [64*16384];
__device__ __align__(16) float  g_t2 [64*16384];
__device__ __align__(16) float  g_t3 [64*8320];
__device__ __align__(16) float  g_t4 [64*8320];
__device__ __align__(16) float  g_cat[4*48*16384];

// ---------------- builder body -----------------------------------------------
__device__ inline void build_A_body(int tid) {
    if (tid >= 128*128) return;
    int o = tid >> 7, m = tid & 127;
    const double chc = -PI_D/128.0 * tan(PI_D/8.0) * 0.25;
    const double c   =  PI_D/(512.0*sin(PI_D/4.0));
    const double inv2pi = 1.0/(2.0*PI_D);
    float sr, si;
    {   // q = 2m term (sinc = 1)
        int n1 = 2*m - 127, tt = 2*(o - m);
        double ang = chc*(double)(n1*n1) + c*(double)(tt*tt);
        double r = ang*inv2pi; r -= floor(r);
        float af = (float)(r*2.0*PI_D);
        float sn, cs; __sincosf(af, &sn, &cs);
        sr = cs; si = sn;
    }
    for (int j = 0; j < 127; ++j) {
        int q  = 2*j + 1;
        int n1 = q - 127, tt = 2*o - q, d = q - 2*m;
        double ang = chc*(double)(n1*n1) + c*(double)(tt*tt);
        double r = ang*inv2pi; r -= floor(r);
        float af = (float)(r*2.0*PI_D);
        float s = (((d-1)>>1) & 1) ? -2.0f : 2.0f;
        s /= (3.14159265358979f*(float)d);
        float sn, cs; __sincosf(af, &sn, &cs);
        sr += s*cs; si += s*sn;
    }
    int n2 = 2*o - 127;
    double ph = chc*(double)(n2*n2) - PI_D/8.0;
    double r = ph*inv2pi; r -= floor(r);
    float pf = (float)(r*2.0*PI_D);
    float scale = (float)sqrt(c/PI_D);
    float sn, cs; __sincosf(pf, &sn, &cs);
    float cr = cs*scale, ci = sn*scale;
    float2 v = make_float2(sr*cr - si*ci, sr*ci + si*cr);
    g_Mf[tid] = v;
    g_MfT[(m<<7) + o] = v;
    int p = (o*m) & 127;
    float ang2 = TWO_PI_F*(float)p/128.0f;
    float sn2, cs2; __sincosf(ang2, &sn2, &cs2);
    g_F[tid]  = make_float2(cs2, -sn2);
    g_IF[tid] = make_float2(cs2*0.0078125f, sn2*0.0078125f);
}

// ---------------- stream loaders (rmul T-side) -------------------------------
template<int LM>
__device__ inline void load_T4(float2* tr, const float* mp, const float* pp,
                               const float* Trl, int hh, int w4) {
    if (LM == 1) {
        float4 v = *(const float4*)(Trl + (hh<<7) + w4);
        tr[0] = make_float2(v.x, 0.f); tr[1] = make_float2(v.y, 0.f);
        tr[2] = make_float2(v.z, 0.f); tr[3] = make_float2(v.w, 0.f);
    } else if (LM == 2) {
#pragma unroll
        for (int i = 0; i < 4; ++i) {
            int idx = (hh<<7) + w4 + i;
            float m = mp[idx], ph = pp[idx];
            float sn, cs; __sincosf(ph, &sn, &cs);
            tr[i] = make_float2(m*cs, m*sn);
        }
    } else {
#pragma unroll
        for (int i = 0; i < 4; ++i) {
            int w = w4 + i;
            int h2 = hh, w2 = w; float sg = 1.f;
            if (w >= 65) { h2 = (128 - hh) & 127; w2 = 128 - w; sg = -1.f; }
            int idx = h2*65 + w2;
            float m = mp[idx], ph = pp[idx];
            float sn, cs; __sincosf(ph, &sn, &cs);
            tr[i] = make_float2(m*cs, sg*m*sn);
        }
    }
}

__device__ inline void cfma(float2& a, float sx, float sy, float mx, float my) {
    a.x = fmaf(sx, mx, a.x); a.x = fmaf(-sy, my, a.x);
    a.y = fmaf(sx, my, a.y); a.y = fmaf(sy, mx, a.y);
}

// ---------------- rmul body: out[p,h,j] = sum_w T[p,h,w] * A[j,w] ------------
// Ssh = 16-row stream strip (full 128 k); Mch = 16-k chunk of A^T [k][j].
template<int LM>
__device__ inline void rmul_body(const float2* __restrict__ MT, const float* __restrict__ Trl,
                                 const float* __restrict__ mp_, const float* __restrict__ pp_,
                                 float2* __restrict__ out, int cstart,
                                 int p, int r0, int t, float2* Ssh, float2* Mch) {
    constexpr bool RS = (LM == 1);
    const float* Trp = nullptr; const float* mp = nullptr; const float* pp = nullptr;
    if (LM == 1) { int n = p >> 4, c = p & 15; Trp = Trl + ((long)(n*48 + cstart + c) << 14); }
    if (LM == 2) { mp = mp_ + ((long)p << 14); pp = pp_ + ((long)p << 14); }
    if (LM == 3) { mp = mp_ + (long)p*8320;   pp = pp_ + (long)p*8320; }
    for (int u = t; u < 512; u += 256) {
        int row = u >> 5, w4 = (u & 31) << 2;
        float2 tr4[4];
        load_T4<LM>(tr4, mp, pp, Trp, r0 + row, w4);
        float4* d = (float4*)&Ssh[(row << 7) + w4];
        d[0] = make_float4(tr4[0].x, tr4[0].y, tr4[1].x, tr4[1].y);
        d[1] = make_float4(tr4[2].x, tr4[2].y, tr4[3].x, tr4[3].y);
    }
    float2 acc[4][2] = {};
    int cq = t & 63, rp = t >> 6;
    for (int kc = 0; kc < 128; kc += 16) {
        __syncthreads();
        {
            const float4* Mg = (const float4*)(MT + (kc << 7));
            float4* Md = (float4*)Mch;
            for (int i = t; i < 1024; i += 256) Md[i] = Mg[i];
        }
        __syncthreads();
#pragma unroll
        for (int kk = 0; kk < 16; kk += 2) {
            float4 s2[4];
#pragma unroll
            for (int i = 0; i < 4; ++i)
                s2[i] = *(const float4*)&Ssh[(((rp<<2)+i) << 7) + kc + kk];
            float4 m0 = *(const float4*)&Mch[(kk << 7) + (cq<<1)];
            float4 m1 = *(const float4*)&Mch[((kk+1) << 7) + (cq<<1)];
#pragma unroll
            for (int i = 0; i < 4; ++i) {
                if (RS) {
                    acc[i][0].x = fmaf(s2[i].x, m0.x, acc[i][0].x);
                    acc[i][0].y = fmaf(s2[i].x, m0.y, acc[i][0].y);
                    acc[i][1].x = fmaf(s2[i].x, m0.z, acc[i][1].x);
                    acc[i][1].y = fmaf(s2[i].x, m0.w, acc[i][1].y);
                    acc[i][0].x = fmaf(s2[i].z, m1.x, acc[i][0].x);
                    acc[i][0].y = fmaf(s2[i].z, m1.y, acc[i][0].y);
                    acc[i][1].x = fmaf(s2[i].z, m1.z, acc[i][1].x);
                    acc[i][1].y = fmaf(s2[i].z, m1.w, acc[i][1].y);
                } else {
                    cfma(acc[i][0], s2[i].x, s2[i].y, m0.x, m0.y);
                    cfma(acc[i][1], s2[i].x, s2[i].y, m0.z, m0.w);
                    cfma(acc[i][0], s2[i].z, s2[i].w, m1.x, m1.y);
                    cfma(acc[i][1], s2[i].z, s2[i].w, m1.z, m1.w);
                }
            }
        }
    }
    long base = ((long)p << 14);
#pragma unroll
    for (int i = 0; i < 4; ++i) {
        float4* dst = (float4*)(out + base + ((long)(r0 + (rp<<2) + i) << 7) + (cq<<1));
        *dst = make_float4(acc[i][0].x, acc[i][0].y, acc[i][1].x, acc[i][1].y);
    }
}

// ---------------- lmul body: out[p,j,w] = sum_h A[j,h] * T[p,h,w] ------------
// EPI 1: mag/pha full  2: abs->cat+coff  3: real-only->cat+coff  4: packed65
template<int EPI>
__device__ inline void lmul_body(const float2* __restrict__ A, const float2* __restrict__ in,
                                 float* __restrict__ o1, float* __restrict__ o2, int coff,
                                 int p, int j0, int t, float2* Ssh, float2* Tch) {
    const float2* T = in + ((long)p << 14);
    {
        const float4* Ag = (const float4*)(A + ((long)j0 << 7));
        float4* Sd = (float4*)Ssh;
        for (int i = t; i < 1024; i += 256) Sd[i] = Ag[i];
    }
    float2 acc[4][2] = {};
    int cq = t & 63, rp = t >> 6;
    for (int kc = 0; kc < 128; kc += 16) {
        __syncthreads();
        {
            const float4* Tg = (const float4*)(T + (kc << 7));
            float4* Td = (float4*)Tch;
            for (int i = t; i < 1024; i += 256) Td[i] = Tg[i];
        }
        __syncthreads();
#pragma unroll
        for (int kk = 0; kk < 16; kk += 2) {
            float4 s2[4];
#pragma unroll
            for (int i = 0; i < 4; ++i)
                s2[i] = *(const float4*)&Ssh[(((rp<<2)+i) << 7) + kc + kk];
            float4 m0 = *(const float4*)&Tch[(kk << 7) + (cq<<1)];
            float4 m1 = *(const float4*)&Tch[((kk+1) << 7) + (cq<<1)];
#pragma unroll
            for (int i = 0; i < 4; ++i) {
                if (EPI == 3) {
                    acc[i][0].x = fmaf(s2[i].x, m0.x, acc[i][0].x);
                    acc[i][0].x = fmaf(-s2[i].y, m0.y, acc[i][0].x);
                    acc[i][1].x = fmaf(s2[i].x, m0.z, acc[i][1].x);
                    acc[i][1].x = fmaf(-s2[i].y, m0.w, acc[i][1].x);
                    acc[i][0].x = fmaf(s2[i].z, m1.x, acc[i][0].x);
                    acc[i][0].x = fmaf(-s2[i].w, m1.y, acc[i][0].x);
                    acc[i][1].x = fmaf(s2[i].z, m1.z, acc[i][1].x);
                    acc[i][1].x = fmaf(-s2[i].w, m1.w, acc[i][1].x);
                } else {
                    cfma(acc[i][0], s2[i].x, s2[i].y, m0.x, m0.y);
                    cfma(acc[i][1], s2[i].x, s2[i].y, m0.z, m0.w);
                    cfma(acc[i][0], s2[i].z, s2[i].w, m1.x, m1.y);
                    cfma(acc[i][1], s2[i].z, s2[i].w, m1.z, m1.w);
                }
            }
        }
    }
#pragma unroll
    for (int i = 0; i < 4; ++i) {
        int jj = j0 + (rp<<2) + i;
        int ww0 = cq << 1;
        float2 v0 = acc[i][0], v1 = acc[i][1];
        if (EPI == 1) {
            long idx = ((long)p << 14) + ((long)jj << 7) + ww0;
            *(float2*)&o1[idx] = make_float2(sqrtf(v0.x*v0.x + v0.y*v0.y),
                                             sqrtf(v1.x*v1.x + v1.y*v1.y));
            *(float2*)&o2[idx] = make_float2(atan2f(v0.y, v0.x), atan2f(v1.y, v1.x));
        } else if (EPI == 2) {
            int n = p >> 4, c = p & 15;
            long idx = ((long)(n*48 + coff + c) << 14) + ((long)jj << 7) + ww0;
            *(float2*)&o1[idx] = make_float2(sqrtf(v0.x*v0.x + v0.y*v0.y),
                                             sqrtf(v1.x*v1.x + v1.y*v1.y));
        } else if (EPI == 3) {
            int n = p >> 4, c = p & 15;
            long idx = ((long)(n*48 + coff + c) << 14) + ((long)jj << 7) + ww0;
            *(float2*)&o1[idx] = make_float2(v0.x, v1.x);
        } else if (EPI == 4) {
            if (ww0 < 65) {
                long idx = (long)p*8320 + jj*65 + ww0;
                o1[idx] = sqrtf(v0.x*v0.x + v0.y*v0.y);
                o2[idx] = atan2f(v0.y, v0.x);
                if (ww0 + 1 < 65) {
                    o1[idx+1] = sqrtf(v1.x*v1.x + v1.y*v1.y);
                    o2[idx+1] = atan2f(v1.y, v1.x);
                }
            }
        }
    }
}

// ---------------- dual rmul kernel (+ Mb build at bx>=128) -------------------
// grid (136, 8): bx<128 -> plane (A: 0..63, B: 64..127), by = strip.
// id % 8 == bx % 8 -> all strips of a plane land on one XCD.
template<int LMA, int LMB>
__global__ __launch_bounds__(256, 4)
void k_rmul_dual(const float2* __restrict__ MTa, const float* __restrict__ TrlA,
                 const float* __restrict__ mpA, const float* __restrict__ ppA,
                 float2* __restrict__ outA, int cstartA,
                 const float2* __restrict__ MTb, const float* __restrict__ TrlB,
                 const float* __restrict__ mpB, const float* __restrict__ ppB,
                 float2* __restrict__ outB, int cstartB) {
    __shared__ float2 Ssh[16*128];
    __shared__ float2 Mch[16*128];
    __shared__ float2 W[128];
    int bx = blockIdx.x, by = blockIdx.y, t = threadIdx.x;
    if (bx >= 128) {
        int b = (bx - 128)*8 + by;
        if (b < 64) {
            if (t < 128) {
                float ang = TWO_PI_F*(float)t/128.0f;
                float sn, cs; __sincosf(ang, &sn, &cs);
                float invs = 0.08838834764831845f;
                W[t] = make_float2(cs*invs, sn*invs);
            }
            __syncthreads();
            int tid = b*256 + t;
            int o = tid >> 7, m = tid & 127;
            float sr = 0.f, si = 0.f;
            for (int r = 0; r < 128; ++r) {
                float2 a = g_Mf[(o<<7) + r];
                int k = ((r+64)*(m+64)) & 127;
                float2 w = W[k];
                sr += a.x*w.x - a.y*w.y;
                si += a.x*w.y + a.y*w.x;
            }
            float2 v = make_float2(sr, si);
            g_Mb[tid] = v;
            g_MbT[(m<<7) + o] = v;
        }
        return;
    }
    int p = bx & 63, r0 = by << 4;
    if (bx < 64) rmul_body<LMA>(MTa, TrlA, mpA, ppA, outA, cstartA, p, r0, t, Ssh, Mch);
    else         rmul_body<LMB>(MTb, TrlB, mpB, ppB, outB, cstartB, p, r0, t, Ssh, Mch);
}

// ---------------- dual lmul kernel (XCD-pinned planes) -----------------------
template<int EPIA, int EPIB>
__global__ __launch_bounds__(256, 4)
void k_lmul_dual(const float2* __restrict__ Aa, const float2* __restrict__ inA,
                 float* __restrict__ o1A, float* __restrict__ o2A, int coffA,
                 const float2* __restrict__ Ab, const float2* __restrict__ inB,
                 float* __restrict__ o1B, float* __restrict__ o2B, int coffB) {
    __shared__ float2 Ssh[16*128];
    __shared__ float2 Tch[16*128];
    int bx = blockIdx.x, j0 = blockIdx.y << 4, t = threadIdx.x;
    int p = bx & 63;
    if (bx < 64) lmul_body<EPIA>(Aa, inA, o1A, o2A, coffA, p, j0, t, Ssh, Tch);
    else         lmul_body<EPIB>(Ab, inB, o1B, o2B, coffB, p, j0, t, Ssh, Tch);
}

// ---------------- wave-level 1x1 conv body -----------------------------------
template<int CIN, int COUT, int KSPLIT, int OSPLIT>
__device__ inline void wconv_body(const float* __restrict__ in, const float* __restrict__ wgt,
                                  const float* __restrict__ bias, float* __restrict__ out,
                                  int S, int Ctin, int cstart, int Ctout, int costart,
                                  int n, int sblk, float* red) {
    constexpr int OW = COUT / OSPLIT;
    constexpr int KC = CIN / KSPLIT;
    int t = threadIdx.x, lane = t & 63;
    int wv = __builtin_amdgcn_readfirstlane(t >> 6);
    int oq = wv / KSPLIT, kq = wv % KSPLIT;
    int s0 = sblk << 7;
    const float* inb = in + ((long)(n*Ctin + cstart + kq*KC))*S + s0 + (lane<<1);
    const float* wb  = wgt + (oq*OW)*CIN + kq*KC;
    float2 acc[OW];
#pragma unroll
    for (int j = 0; j < OW; ++j) acc[j] = make_float2(0.f, 0.f);
#pragma unroll 4
    for (int c = 0; c < KC; ++c) {
        float2 xv = *(const float2*)(inb + (long)c*S);
#pragma unroll
        for (int j = 0; j < OW; ++j) {
            float w = wb[j*CIN + c];
            acc[j].x = fmaf(w, xv.x, acc[j].x);
            acc[j].y = fmaf(w, xv.y, acc[j].y);
        }
    }
    if (KSPLIT == 1) {
#pragma unroll
        for (int j = 0; j < OW; ++j) {
            int o = oq*OW + j;
            float b = bias ? bias[o] : 0.f;
            *(float2*)(out + ((long)(n*Ctout + costart + o))*S + s0 + (lane<<1))
                = make_float2(acc[j].x + b, acc[j].y + b);
        }
    } else {
#pragma unroll
        for (int j = 0; j < OW; ++j) {
            int o = oq*OW + j;
            *(float2*)&red[((kq*COUT + o) << 7) + (lane<<1)] = acc[j];
        }
        __syncthreads();
        for (int idx = t; idx < COUT*64; idx += 256) {
            int o = idx >> 6, l2 = (idx & 63) << 1;
            float b = bias ? bias[o] : 0.f;
            float2 v = make_float2(b, b);
#pragma unroll
            for (int k2 = 0; k2 < KSPLIT; ++k2) {
                float2 r = *(const float2*)&red[((k2*COUT + o) << 7) + l2];
                v.x += r.x; v.y += r.y;
            }
            *(float2*)(out + ((long)(n*Ctout + costart + o))*S + s0 + l2) = v;
        }
    }
}

// ---------------- stage 1: conv1 + matrix builder ----------------------------
__global__ __launch_bounds__(256, 1)
void k_conv1_build(const float* __restrict__ x, const float* __restrict__ w,
                   float* __restrict__ x1) {
    __shared__ float red[2*48*128];
    if (blockIdx.z == 0) {
        wconv_body<192,48,2,2>(x, w, nullptr, x1, 16384, 192, 0, 48, 0,
                               blockIdx.y, blockIdx.x, red);
    } else {
        int b = blockIdx.y*gridDim.x + blockIdx.x;
        if (b < 64) build_A_body(b*256 + threadIdx.x);
    }
}

// ---------------- stage 7: conv2 ---------------------------------------------
__global__ __launch_bounds__(256, 1)
void k_conv2(const float* __restrict__ in, const float* __restrict__ wgt,
             float* __restrict__ out) {
    __shared__ float red[1];
    wconv_body<48,192,1,4>(in, wgt, nullptr, out, 16384, 48, 0, 192, 0,
                           blockIdx.y, blockIdx.x, red);
}

// ---------------- pointwise stage: maskconv + 4 channel-mixes ----------------
__device__ inline void mix16b(const float* __restrict__ in, const float* __restrict__ w,
                              const float* __restrict__ b, float* __restrict__ out,
                              int Ctin, int S, int n, int s0) {
    int t = threadIdx.x, lane = t & 63;
    int oq = __builtin_amdgcn_readfirstlane(t >> 6);
    const float* inb = in + ((long)(n*Ctin))*S + s0 + (lane<<1);
    float2 xv[16];
#pragma unroll
    for (int c = 0; c < 16; ++c) xv[c] = *(const float2*)(inb + (long)c*S);
#pragma unroll
    for (int j = 0; j < 4; ++j) {
        int o = oq*4 + j;
        float bb = b ? b[o] : 0.f;
        float2 a = make_float2(bb, bb);
#pragma unroll
        for (int c = 0; c < 16; ++c) {
            float ww = w[o*16 + c];
            a.x = fmaf(ww, xv[c].x, a.x);
            a.y = fmaf(ww, xv[c].y, a.y);
        }
        *(float2*)(out + ((long)(n*Ctin + o))*S + s0 + (lane<<1)) = a;
    }
}

__device__ inline void maskconv_body(const float* __restrict__ mag, const float* __restrict__ ws3,
                                     const float* __restrict__ bs, const float* __restrict__ wf,
                                     const float* __restrict__ bf, const float* __restrict__ wm,
                                     const float* __restrict__ bm, float* __restrict__ out,
                                     int n, int tile, float (*patch)[324]) {
    int h0 = (tile >> 3) << 4, w0 = (tile & 7) << 4;
    int t = threadIdx.x;
    const float* magn = mag + ((long)n << 18);
    for (int idx = t; idx < 16*324; idx += 256) {
        int c = idx / 324, r = idx - c*324;
        int ph = r / 18, pw = r - ph*18;
        int gh = h0 - 1 + ph, gw = w0 - 1 + pw;
        float v = 0.f;
        if (gh >= 19 && gh < 109 && gw >= 19 && gw < 109)
            v = magn[(c<<14) + (gh<<7) + gw];
        patch[c][r] = v;
    }
    __syncthreads();
    int ty = t >> 4, tx = t & 15;
    int h = h0 + ty, w = w0 + tx;
    bool in1 = (h >= 19 && h < 109 && w >= 19 && w < 109);
    unsigned long long bal = __ballot(in1);
    float res[16];
    if (bal != 0ull) {
        float acc[16];
#pragma unroll
        for (int o = 0; o < 16; ++o) acc[o] = bs[o];
        for (int c = 0; c < 16; ++c) {
            float tap[9];
#pragma unroll
            for (int dh = 0; dh < 3; ++dh)
#pragma unroll
                for (int dw = 0; dw < 3; ++dw)
                    tap[dh*3+dw] = patch[c][(ty+dh)*18 + tx+dw];
            const float* wp = ws3 + c*9;
#pragma unroll
            for (int o = 0; o < 16; ++o)
#pragma unroll
                for (int k = 0; k < 9; ++k)
                    acc[o] = fmaf(wp[o*144 + k], tap[k], acc[o]);
        }
#pragma unroll
        for (int o = 0; o < 16; ++o) res[o] = acc[o];
    }
    if (bal != ~0ull) {
        float xv[16];
#pragma unroll
        for (int c = 0; c < 16; ++c) xv[c] = magn[(c<<14) + (h<<7) + w];
#pragma unroll
        for (int o = 0; o < 16; ++o) {
            float a = bf[o];
#pragma unroll
            for (int c = 0; c < 16; ++c) a = fmaf(wf[o*16 + c], xv[c], a);
            if (!in1) res[o] = a;
        }
    }
#pragma unroll
    for (int o2 = 0; o2 < 16; ++o2) {
        float a = bm[o2];
#pragma unroll
        for (int o = 0; o < 16; ++o)
            a = fmaf(wm[o2*16 + o], res[o], a);
        out[((long)((n<<4) + o2) << 14) + (h << 7) + w] = a;
    }
}

__global__ __launch_bounds__(256, 2)
void k_point(const float* __restrict__ mag, const float* __restrict__ ws3,
             const float* __restrict__ bs, const float* __restrict__ wf,
             const float* __restrict__ bf, const float* __restrict__ wm,
             const float* __restrict__ bm, float* __restrict__ t2,
             const float* __restrict__ pha, const float* __restrict__ pw,
             const float* __restrict__ pb, float* __restrict__ t1,
             const float* __restrict__ x1, const float* __restrict__ c0w,
             const float* __restrict__ c0b, float* __restrict__ cat,
             const float* __restrict__ m65, const float* __restrict__ p65,
             const float* __restrict__ c1w, const float* __restrict__ c1b,
             float* __restrict__ t3, float* __restrict__ t4) {
    __shared__ float patch[16][324];
    int b = blockIdx.x;
    if (b < 256) {
        maskconv_body(mag, ws3, bs, wf, bf, wm, bm, t2, b >> 6, b & 63, patch);
    } else if (b < 768) {
        int i = b - 256;               // pha channel-mix (S=16384)
        mix16b(pha, pw, pb, t1, 16, 16384, i >> 7, (i & 127) << 7);
    } else if (b < 1280) {
        int i = b - 768;               // conv_0: x1 ch0..15 -> cat ch0..15 (Ct=48)
        mix16b(x1, c0w, c0b, cat, 48, 16384, i >> 7, (i & 127) << 7);
    } else if (b < 1540) {
        int i = b - 1280;              // m65 mix (S=8320)
        mix16b(m65, c1w, c1b, t3, 16, 8320, i / 65, (i % 65) << 7);
    } else {
        int i = b - 1540;              // p65 mix
        mix16b(p65, c1w, c1b, t4, 16, 8320, i / 65, (i % 65) << 7);
    }
}

// ---------------- launch ----------------------------------------------------
extern "C" void kernel_launch(void* const* d_in, const int* in_sizes, int n_in,
                              void* d_out, int out_size, void* d_ws, size_t ws_size,
                              hipStream_t stream) {
    (void)in_sizes; (void)n_in; (void)out_size; (void)d_ws; (void)ws_size;
    const float* x        = (const float*)d_in[0];
    const float* conv1_w  = (const float*)d_in[1];
    const float* mag_s_w  = (const float*)d_in[2];
    const float* mag_s_b  = (const float*)d_in[3];
    const float* mag_f_w  = (const float*)d_in[4];
    const float* mag_f_b  = (const float*)d_in[5];
    const float* mag_w_   = (const float*)d_in[6];
    const float* mag_b_   = (const float*)d_in[7];
    const float* pha_w_   = (const float*)d_in[8];
    const float* pha_b_   = (const float*)d_in[9];
    const float* conv_0_w = (const float*)d_in[10];
    const float* conv_0_b = (const float*)d_in[11];
    const float* conv_1_w = (const float*)d_in[12];
    const float* conv_1_b = (const float*)d_in[13];
    const float* conv2_w  = (const float*)d_in[14];
    float* outp = (float*)d_out;

    float2 *Mf, *MfT, *Mb, *MbT, *Fm, *IFm, *bufA, *bufB;
    float *x1, *mag, *pha, *m65, *p65, *t1, *t2, *t3, *t4, *cat;
    hipGetSymbolAddress((void**)&Mf,   HIP_SYMBOL(g_Mf));
    hipGetSymbolAddress((void**)&MfT,  HIP_SYMBOL(g_MfT));
    hipGetSymbolAddress((void**)&Mb,   HIP_SYMBOL(g_Mb));
    hipGetSymbolAddress((void**)&MbT,  HIP_SYMBOL(g_MbT));
    hipGetSymbolAddress((void**)&Fm,   HIP_SYMBOL(g_F));
    hipGetSymbolAddress((void**)&IFm,  HIP_SYMBOL(g_IF));
    hipGetSymbolAddress((void**)&bufA, HIP_SYMBOL(g_bufA));
    hipGetSymbolAddress((void**)&bufB, HIP_SYMBOL(g_bufB));
    hipGetSymbolAddress((void**)&x1,   HIP_SYMBOL(g_x1));
    hipGetSymbolAddress((void**)&mag,  HIP_SYMBOL(g_mag));
    hipGetSymbolAddress((void**)&pha,  HIP_SYMBOL(g_pha));
    hipGetSymbolAddress((void**)&m65,  HIP_SYMBOL(g_m65));
    hipGetSymbolAddress((void**)&p65,  HIP_SYMBOL(g_p65));
    hipGetSymbolAddress((void**)&t1,   HIP_SYMBOL(g_t1));
    hipGetSymbolAddress((void**)&t2,   HIP_SYMBOL(g_t2));
    hipGetSymbolAddress((void**)&t3,   HIP_SYMBOL(g_t3));
    hipGetSymbolAddress((void**)&t4,   HIP_SYMBOL(g_t4));
    hipGetSymbolAddress((void**)&cat,  HIP_SYMBOL(g_cat));

    dim3 bt(256, 1, 1);

    // stage 1: conv1 (x -> x1) + build Mf/MfT/F/IF
    k_conv1_build<<<dim3(128,4,2), bt, 0, stream>>>(x, conv1_w, x1);

    // stage 2: dual rmul (FRFT fwd -> bufA; FFT fwd -> bufB) + build Mb
    k_rmul_dual<1,1><<<dim3(136,8), bt, 0, stream>>>(
        MfT, x1, nullptr, nullptr, bufA, 16,
        Fm,  x1, nullptr, nullptr, bufB, 32);

    // stage 3: dual lmul (mag/pha full <- bufA; packed65 <- bufB)
    k_lmul_dual<1,4><<<dim3(128,8), bt, 0, stream>>>(
        Mf, bufA, mag, pha, 0,
        Fm, bufB, m65, p65, 0);

    // stage 4: maskconv(+mag mix) | pha mix | conv_0 | m65 mix | p65 mix
    k_point<<<1800, bt, 0, stream>>>(mag, mag_s_w, mag_s_b, mag_f_w, mag_f_b,
                                     mag_w_, mag_b_, t2,
                                     pha, pha_w_, pha_b_, t1,
                                     x1, conv_0_w, conv_0_b, cat,
                                     m65, p65, conv_1_w, conv_1_b, t3, t4);

    // stage 5: dual rmul (FRFT bwd combine(t2,t1) -> bufA; irfft combine65(t3,t4) -> bufB)
    k_rmul_dual<2,3><<<dim3(128,8), bt, 0, stream>>>(
        MbT, nullptr, t2, t1, bufA, 0,
        IFm, nullptr, t3, t4, bufB, 0);

    // stage 6: dual lmul (abs -> cat ch16..31; real -> cat ch32..47)
    k_lmul_dual<2,3><<<dim3(128,8), bt, 0, stream>>>(
        Mb,  bufA, cat, nullptr, 16,
        IFm, bufB, cat, nullptr, 32);

    // stage 7: conv2 (cat -> out)
    k_conv2<<<dim3(128,4), bt, 0, stream>>>(cat, conv2_w, outp);
}